// Round 12
// baseline (3899.884 us; speedup 1.0000x reference)
//
#include <hip/hip_runtime.h>

#define NCONV_DEF 4
#define SCH 1024

typedef unsigned short u16;
typedef __attribute__((ext_vector_type(8))) short s8v;      // MFMA bf16 A/B frag
typedef __attribute__((ext_vector_type(4))) float f4v;      // MFMA C/D frag
typedef __attribute__((ext_vector_type(8))) unsigned short u16x8;

__device__ __forceinline__ float sigm_f(float x){ return 1.f/(1.f+__expf(-x)); }
__device__ __forceinline__ float silu_f(float x){ return x/(1.f+__expf(-x)); }
__device__ __forceinline__ float b2f(u16 h){ union{unsigned u; float f;} v; v.u=(unsigned)h<<16; return v.f; }
__device__ __forceinline__ u16 f2b(float f){ union{float f; unsigned u;} v; v.f=f; unsigned r=v.u+0x7fffu+((v.u>>16)&1u); return (u16)(r>>16); }
__device__ __forceinline__ float ldAv(const float* p, size_t i){ return p[i]; }
__device__ __forceinline__ float ldAv(const u16* p, size_t i){ return b2f(p[i]); }

#define EPS_ 136   // epilogue LDS row stride in u16 (272B)

__global__ __launch_bounds__(256) void zero_f_k(float* p, long n){
    long i=(long)blockIdx.x*256+threadIdx.x, st=(long)gridDim.x*256;
    for(;i<n;i+=st) p[i]=0.f;
}
__global__ __launch_bounds__(256) void zero_i_k(int* p, long n){
    long i=(long)blockIdx.x*256+threadIdx.x, st=(long)gridDim.x*256;
    for(;i<n;i+=st) p[i]=0;
}
__global__ void diag_k(float* out, int n, float v){
    int i=blockIdx.x*256+threadIdx.x; if(i<n) out[i]=v;
}
__global__ void probe_k(const int* ei, const int* eil, const int* batch, int nb, int* flag){
    if(threadIdx.x||blockIdx.x) return;
    int a=2,b=2,c=2;
    for(int k=0;k<64;k++){ if(ei[2*k+1]!=0) a=1; if(eil[2*k+1]!=0) b=1; }
    int base=nb-128;
    for(int k=0;k<64;k++){ if(batch[base+2*k+1]!=0) c=1; }
    flag[0]=a; flag[1]=b; flag[2]=c;
}

// ---------------- CSR build ----------------------------------------------------
__global__ __launch_bounds__(256)
void hist_k(const int* __restrict__ idx, const int* __restrict__ iflag, int fi,
            int* __restrict__ cnt, int Ne, int Nn){
    int e=blockIdx.x*256+threadIdx.x; if(e>=Ne) return;
    int st=iflag[fi];
    int i=idx[(size_t)e*st]; i=i<0?0:(i>=Nn?Nn-1:i);
    atomicAdd(&cnt[i],1);
}
__global__ __launch_bounds__(256)
void scan1_k(const int* cnt, int* tot, int n){
    __shared__ int sh[256];
    int base=blockIdx.x*SCH, s=0;
    for(int t=threadIdx.x;t<SCH;t+=256){ int i=base+t; s+=(i<n)?cnt[i]:0; }
    sh[threadIdx.x]=s; __syncthreads();
    for(int o=128;o;o>>=1){ if(threadIdx.x<o) sh[threadIdx.x]+=sh[threadIdx.x+o]; __syncthreads(); }
    if(threadIdx.x==0) tot[blockIdx.x]=sh[0];
}
__global__ void scan2_k(int* tot, int nb){
    if(threadIdx.x==0&&blockIdx.x==0){ int acc=0; for(int i=0;i<nb;i++){int v=tot[i]; tot[i]=acc; acc+=v;} }
}
__global__ __launch_bounds__(256)
void scan3_k(const int* cnt, const int* tot, int* off, int n, int total){
    __shared__ int sh[256];
    int b=blockIdx.x, t4=b*SCH+threadIdx.x*4;
    int v0=(t4+0<n)?cnt[t4+0]:0, v1=(t4+1<n)?cnt[t4+1]:0;
    int v2=(t4+2<n)?cnt[t4+2]:0, v3=(t4+3<n)?cnt[t4+3]:0;
    int ls=v0+v1+v2+v3;
    sh[threadIdx.x]=ls; __syncthreads();
    for(int o=1;o<256;o<<=1){
        int val=(threadIdx.x>=o)?sh[threadIdx.x-o]:0; __syncthreads();
        sh[threadIdx.x]+=val; __syncthreads();
    }
    int excl=sh[threadIdx.x]-ls+tot[b];
    if(t4+0<n) off[t4+0]=excl;
    if(t4+1<n) off[t4+1]=excl+v0;
    if(t4+2<n) off[t4+2]=excl+v0+v1;
    if(t4+3<n) off[t4+3]=excl+v0+v1+v2;
    if(b==(int)gridDim.x-1&&threadIdx.x==255) off[n]=total;
}
__global__ __launch_bounds__(256)
void fill_k(const int* __restrict__ idx, const int* __restrict__ iflag, int fi, long joff,
            const int* __restrict__ off, int* __restrict__ cur,
            int* __restrict__ list, int* __restrict__ jlist, int Ne, int Nn){
    int e=blockIdx.x*256+threadIdx.x; if(e>=Ne) return;
    int st=iflag[fi];
    int i=idx[(size_t)e*st]; i=i<0?0:(i>=Nn?Nn-1:i);
    int j=idx[((size_t)joff+e)*st]; j=j<0?0:(j>=Nn?Nn-1:j);
    int pos=off[i]+atomicAdd(&cur[i],1);
    list[pos]=e; jlist[pos]=j;
}

// ---------------- weight pack: W[K][128] f32 -> Wp[128][Kp] bf16 ---------------
__global__ __launch_bounds__(256)
void pack_w_k(const float* __restrict__ W, u16* __restrict__ Wp, int K, int Kp){
    int i=blockIdx.x*256+threadIdx.x;
    if(i>=128*Kp) return;
    int n=i/Kp, k=i-n*Kp;
    Wp[i] = (k<K) ? f2b(W[(size_t)k*128+n]) : (u16)0;
}

// ---------------- MFMA GEMM: C[M,128] = A[M,K] @ W[K,128] (+bias)(+silu) -------
template<typename TA, int ACT>
__global__ __launch_bounds__(256)
void gemm_k(const TA* __restrict__ A, int lda, int M, int K, int Kp,
            const u16* __restrict__ Wp, const float* __restrict__ bias,
            u16* __restrict__ C)
{
    __shared__ __align__(16) u16 As[64*72];
    __shared__ __align__(16) u16 Bs[128*72];
    const int tid=threadIdx.x, row0=blockIdx.x*64;
    const int w=tid>>6, l=tid&63, lr=l&15, kg=l>>4;
    f4v zz={0.f,0.f,0.f,0.f};
    f4v acc[8];
#pragma unroll
    for(int i=0;i<8;++i) acc[i]=zz;

    for(int kt=0;kt<Kp;kt+=64){
        {
            int r=tid>>2, c0=(tid&3)*16;
            int gr=row0+r;
            bool vec=false;
            if constexpr (sizeof(TA)==2) vec=((K&63)==0);
            if(vec){
                const u16* src=(const u16*)(const void*)A+(size_t)gr*lda+kt+c0;
                u16x8 v0={0,0,0,0,0,0,0,0}, v1={0,0,0,0,0,0,0,0};
                if(gr<M){ v0=*(const u16x8*)src; v1=*(const u16x8*)(src+8); }
                *(u16x8*)&As[r*72+c0]=v0;
                *(u16x8*)&As[r*72+c0+8]=v1;
            } else {
                for(int c=c0;c<c0+16;++c){
                    int k=kt+c;
                    float v=(gr<M&&k<K)?ldAv(A,(size_t)gr*lda+k):0.f;
                    As[r*72+c]=f2b(v);
                }
            }
        }
        {
            int n=tid>>1, k0=(tid&1)*32;
            const u16* src=Wp+(size_t)n*Kp+kt+k0;
            *(u16x8*)&Bs[n*72+k0]   =*(const u16x8*)(src);
            *(u16x8*)&Bs[n*72+k0+8] =*(const u16x8*)(src+8);
            *(u16x8*)&Bs[n*72+k0+16]=*(const u16x8*)(src+16);
            *(u16x8*)&Bs[n*72+k0+24]=*(const u16x8*)(src+24);
        }
        __syncthreads();
        const int arow=w*16+lr;
#pragma unroll
        for(int kk=0;kk<64;kk+=32){
            s8v a=*(const s8v*)&As[arow*72+kk+kg*8];
#pragma unroll
            for(int ct=0;ct<8;++ct){
                s8v bfr=*(const s8v*)&Bs[(ct*16+lr)*72+kk+kg*8];
                acc[ct]=__builtin_amdgcn_mfma_f32_16x16x32_bf16(a,bfr,acc[ct],0,0,0);
            }
        }
        __syncthreads();
    }
    u16* ep=Bs;
#pragma unroll
    for(int ct=0;ct<8;++ct){
        int col=ct*16+lr;
        float bv=bias?bias[col]:0.f;
#pragma unroll
        for(int reg=0;reg<4;++reg){
            float v=acc[ct][reg]+bv;
            if(ACT) v=silu_f(v);
            ep[(w*16+kg*4+reg)*EPS_+col]=f2b(v);
        }
    }
    __syncthreads();
    {
        int ar=tid>>2, gr=row0+ar;
        if(gr<M){
            u16* crow=C+(size_t)gr*128+(tid&3)*32;
            const u16* hrow=&ep[ar*EPS_+(tid&3)*32];
#pragma unroll
            for(int c4=0;c4<4;++c4)
                *(u16x8*)(crow+c4*8)=*(const u16x8*)(hrow+c4*8);
        }
    }
}

// ---------------- partial CSR gather (chunk 0 of line conv): raw a -> U --------
__global__ __launch_bounds__(256)
void gatherp_k(const u16* __restrict__ e, const u16* __restrict__ P1,
               u16* __restrict__ U,
               const int* __restrict__ off, const int* __restrict__ list,
               const int* __restrict__ jlist,
               int Nn, int c0, int c1)
{
    int wid=threadIdx.x>>6, lane=threadIdx.x&63;
    int h=lane>>5, sl=lane&31;
    int n=blockIdx.x*8+wid*2+h;
    int beg=0,end=0;
    if(n<Nn){ beg=off[n]; end=off[n+1]; }
    const int d4=sl*4;
    float a[4]={0.f,0.f,0.f,0.f};
    int k=beg;
    uint2 ev_n, pv_n; ev_n.x=ev_n.y=0; pv_n.x=pv_n.y=0;
    bool in_n=false;
    if(k<end){
        int eid=list[k], j=jlist[k];
        in_n=(j>=c0)&&(j<c1);
        if(in_n){
            ev_n=*(const uint2*)(e+(size_t)eid*128+d4);
            pv_n=*(const uint2*)(P1+(size_t)(j-c0)*128+d4);
        }
    }
    while(k<end){
        uint2 ev=ev_n, pv=pv_n; bool in=in_n;
        int kn=k+1;
        if(kn<end){
            int eid=list[kn], j=jlist[kn];
            in_n=(j>=c0)&&(j<c1);
            ev_n.x=ev_n.y=0; pv_n.x=pv_n.y=0;
            if(in_n){
                ev_n=*(const uint2*)(e+(size_t)eid*128+d4);
                pv_n=*(const uint2*)(P1+(size_t)(j-c0)*128+d4);
            }
        }
        if(in){
            float s0=sigm_f(b2f((u16)(ev.x&0xffff)));
            float s1=sigm_f(b2f((u16)(ev.x>>16)));
            float s2=sigm_f(b2f((u16)(ev.y&0xffff)));
            float s3=sigm_f(b2f((u16)(ev.y>>16)));
            a[0]+=s0*b2f((u16)(pv.x&0xffff));
            a[1]+=s1*b2f((u16)(pv.x>>16));
            a[2]+=s2*b2f((u16)(pv.y&0xffff));
            a[3]+=s3*b2f((u16)(pv.y>>16));
        }
        k=kn;
    }
    if(n>=Nn) return;
    uint2 o;
    o.x=((unsigned)f2b(a[0]))|((unsigned)f2b(a[1])<<16);
    o.y=((unsigned)f2b(a[2]))|((unsigned)f2b(a[3])<<16);
    *(uint2*)(U+(size_t)n*128+d4)=o;
}

// ---------------- FUSED gather-finalize + node-update GEMM ---------------------
// phase1: es over ALL edges + a over [c0,c1) (+ raw prev from Xn) -> gated, LDS ep
// phase2: Xn = X + silu(LN(X@Wsrc + bias + ep))   [out of place]
template<int HASPREV>
__global__ __launch_bounds__(256)
void gatherz_k(const u16* __restrict__ X, u16* __restrict__ Xn,
               const u16* __restrict__ e, const u16* __restrict__ P1,
               const int* __restrict__ off, const int* __restrict__ list,
               const int* __restrict__ jlist,
               const u16* __restrict__ Wp, const float* __restrict__ bias,
               const float* __restrict__ g, const float* __restrict__ b,
               int M, int c0, int c1)
{
    __shared__ __align__(16) u16 As[2][64*68];     // ep aliases this region
    __shared__ __align__(16) u16 Bs[128*136];
    const int tid=threadIdx.x, row0=blockIdx.x*64;
    const int w=tid>>6, l=tid&63, lr=l&15, kg=l>>4;
    const int h=l>>5, sl=l&31, d4=sl*4;
    u16* ep=&As[0][0];

    // ---- phase 1: gather (each wave: 16 nodes, 2 at a time) ----
#pragma unroll 1
    for(int it=0;it<8;++it){
        int nl=w*16+it*2+h, n=row0+nl;
        float es[4]={0.f,0.f,0.f,0.f}, a[4]={0.f,0.f,0.f,0.f};
        if(n<M){
            int beg=off[n], end=off[n+1];
            int k=beg;
            uint2 ev_n, pv_n; ev_n.x=ev_n.y=0; pv_n.x=pv_n.y=0;
            bool in_n=false;
            if(k<end){
                int eid=list[k], j=jlist[k];
                in_n=(j>=c0)&&(j<c1);
                ev_n=*(const uint2*)(e+(size_t)eid*128+d4);
                if(in_n) pv_n=*(const uint2*)(P1+(size_t)(j-c0)*128+d4);
            }
            while(k<end){
                uint2 ev=ev_n, pv=pv_n; bool in=in_n;
                int kn=k+1;
                if(kn<end){
                    int eid=list[kn], j=jlist[kn];
                    in_n=(j>=c0)&&(j<c1);
                    ev_n=*(const uint2*)(e+(size_t)eid*128+d4);
                    pv_n.x=pv_n.y=0;
                    if(in_n) pv_n=*(const uint2*)(P1+(size_t)(j-c0)*128+d4);
                }
                float s0=sigm_f(b2f((u16)(ev.x&0xffff)));
                float s1=sigm_f(b2f((u16)(ev.x>>16)));
                float s2=sigm_f(b2f((u16)(ev.y&0xffff)));
                float s3=sigm_f(b2f((u16)(ev.y>>16)));
                es[0]+=s0; es[1]+=s1; es[2]+=s2; es[3]+=s3;
                if(in){
                    a[0]+=s0*b2f((u16)(pv.x&0xffff));
                    a[1]+=s1*b2f((u16)(pv.x>>16));
                    a[2]+=s2*b2f((u16)(pv.y&0xffff));
                    a[3]+=s3*b2f((u16)(pv.y>>16));
                }
                k=kn;
            }
            if(HASPREV){
                uint2 up=*(const uint2*)(Xn+(size_t)n*128+d4);
                a[0]+=b2f((u16)(up.x&0xffff));
                a[1]+=b2f((u16)(up.x>>16));
                a[2]+=b2f((u16)(up.y&0xffff));
                a[3]+=b2f((u16)(up.y>>16));
            }
        }
        float r0=1.f/(es[0]+1e-5f), r1=1.f/(es[1]+1e-5f);
        float r2=1.f/(es[2]+1e-5f), r3=1.f/(es[3]+1e-5f);
        uint2 o;
        o.x=((unsigned)f2b(a[0]*r0))|((unsigned)f2b(a[1]*r1)<<16);
        o.y=((unsigned)f2b(a[2]*r2))|((unsigned)f2b(a[3]*r3)<<16);
        *(uint2*)(ep+nl*EPS_+d4)=o;
    }
    __syncthreads();
    // ---- phase 2: GEMM + LN + silu + residual ----
    f4v acc[8];
#pragma unroll
    for(int ct=0;ct<8;++ct){
        int col=ct*16+lr;
        float bv=bias[col];
#pragma unroll
        for(int reg=0;reg<4;++reg)
            acc[ct][reg]=b2f(ep[(w*16+kg*4+reg)*EPS_+col])+bv;
    }
    __syncthreads();   // ep reads done before As overwritten

    const int ar=tid>>2, gr=row0+ar;
    {
        int c0c=(tid&3)*16;
        const u16* src=X+(size_t)gr*128;
        u16x8 z8={0,0,0,0,0,0,0,0};
        u16x8 v0=z8,v1=z8,v2=z8,v3=z8;
        if(gr<M){
            v0=*(const u16x8*)(src+c0c);    v1=*(const u16x8*)(src+c0c+8);
            v2=*(const u16x8*)(src+64+c0c); v3=*(const u16x8*)(src+64+c0c+8);
        }
        *(u16x8*)&As[0][ar*68+c0c]=v0;  *(u16x8*)&As[0][ar*68+c0c+8]=v1;
        *(u16x8*)&As[1][ar*68+c0c]=v2;  *(u16x8*)&As[1][ar*68+c0c+8]=v3;
        int bn=tid>>1, bk=(tid&1)*64;
        const u16* wsrc=Wp+(size_t)bn*128+bk;
#pragma unroll
        for(int q=0;q<8;++q)
            *(u16x8*)&Bs[bn*136+bk+q*8]=*(const u16x8*)(wsrc+q*8);
    }
    __syncthreads();
    const int arow=w*16+lr;
#pragma unroll
    for(int kt=0;kt<2;++kt){
#pragma unroll
        for(int kk=0;kk<64;kk+=32){
            s8v a=*(const s8v*)&As[kt][arow*68+kk+kg*8];
#pragma unroll
            for(int ct=0;ct<8;++ct){
                s8v bfr=*(const s8v*)&Bs[(ct*16+lr)*136+kt*64+kk+kg*8];
                acc[ct]=__builtin_amdgcn_mfma_f32_16x16x32_bf16(a,bfr,acc[ct],0,0,0);
            }
        }
    }
    float sum[4]={0.f,0.f,0.f,0.f}, sq[4]={0.f,0.f,0.f,0.f};
#pragma unroll
    for(int ct=0;ct<8;++ct)
#pragma unroll
        for(int reg=0;reg<4;++reg){
            float v=acc[ct][reg];
            sum[reg]+=v; sq[reg]+=v*v;
        }
#pragma unroll
    for(int m=1;m<16;m<<=1)
#pragma unroll
        for(int reg=0;reg<4;++reg){
            sum[reg]+=__shfl_xor(sum[reg],m,64);
            sq[reg] +=__shfl_xor(sq[reg], m,64);
        }
    float mean[4], rstd[4];
#pragma unroll
    for(int reg=0;reg<4;++reg){
        mean[reg]=sum[reg]*(1.f/128.f);
        float var=sq[reg]*(1.f/128.f)-mean[reg]*mean[reg];
        rstd[reg]=rsqrtf(var+1e-5f);
    }
    __syncthreads();   // all MFMA reads of As done before ep overwrite
#pragma unroll
    for(int ct=0;ct<8;++ct){
        int col=ct*16+lr;
        float gv=g[col], bv=b[col];
#pragma unroll
        for(int reg=0;reg<4;++reg){
            float hh=gv*(acc[ct][reg]-mean[reg])*rstd[reg]+bv;
            ep[(w*16+kg*4+reg)*EPS_+col]=f2b(silu_f(hh));
        }
    }
    if(gr<M){
        const u16* xrow=X+(size_t)gr*128+(tid&3)*32;
        u16* orow=Xn+(size_t)gr*128+(tid&3)*32;
        const u16* hrow=&ep[ar*EPS_+(tid&3)*32];
#pragma unroll
        for(int c4=0;c4<4;++c4){
            u16x8 xv=*(const u16x8*)(xrow+c4*8);
            u16x8 hv=*(const u16x8*)(hrow+c4*8);
            u16x8 ov;
#pragma unroll
            for(int j=0;j<8;++j) ov[j]=f2b(b2f(xv[j])+b2f(hv[j]));
            *(u16x8*)(orow+c4*8)=ov;
        }
    }
}

// ---------------- fused edge update: 128 edges, 512 threads, dbuf --------------
__global__ __launch_bounds__(512)
void edgez_k(u16* __restrict__ e, const u16* __restrict__ x,
             const int* __restrict__ idx, long joff,
             const int* __restrict__ iflag, int fi,
             const u16* __restrict__ Wep, const float* __restrict__ be,
             const float* __restrict__ g, const float* __restrict__ b,
             int Ne, int Nn)
{
    __shared__ __align__(16) u16 As[2][128*68];
    __shared__ __align__(16) u16 Bs[2][128*68];
    __shared__ int rid[256];
    const int tid=threadIdx.x, row0=blockIdx.x*128;
    const int w=tid>>6, l=tid&63, lr=l&15, kg=l>>4;
    int st=iflag[fi];
    if(tid<256){
        int r=tid&127, eid=row0+r; if(eid>=Ne) eid=Ne-1;
        long elem=(tid<128)?(long)eid:(joff+eid);
        int v=idx[(size_t)elem*st]; v=v<0?0:(v>=Nn?Nn-1:v);
        rid[tid]=v;
    }
    __syncthreads();
    const int ar=tid>>2, ac=(tid&3)*16;
    const int bn=tid>>2, bk=(tid&3)*16;
    int eidA=row0+ar; if(eidA>=Ne) eidA=Ne-1;
    const u16* aptr0=x+(size_t)rid[ar]*128;
    const u16* aptr1=x+(size_t)rid[128+ar]*128;
    const u16* aptr2=e+(size_t)eidA*128;

    f4v zz={0.f,0.f,0.f,0.f};
    f4v acc[8];
#pragma unroll
    for(int i=0;i<8;++i) acc[i]=zz;

    u16x8 a0,a1,b0,b1;
    u16x8 er0,er1,er2,er3;
    {
        const u16* src=aptr0+ac;
        a0=*(const u16x8*)src; a1=*(const u16x8*)(src+8);
        const u16* wsrc=Wep+(size_t)bn*384+bk;
        b0=*(const u16x8*)wsrc; b1=*(const u16x8*)(wsrc+8);
    }
#pragma unroll
    for(int s=0;s<6;++s){
        const int buf=s&1;
        *(u16x8*)&As[buf][ar*68+ac]  =a0;
        *(u16x8*)&As[buf][ar*68+ac+8]=a1;
        *(u16x8*)&Bs[buf][bn*68+bk]  =b0;
        *(u16x8*)&Bs[buf][bn*68+bk+8]=b1;
        if(s<5){
            const int sn=s+1, sec=sn>>1, half=sn&1;
            const u16* src=(sec==0?aptr0:(sec==1?aptr1:aptr2))+half*64+ac;
            a0=*(const u16x8*)src; a1=*(const u16x8*)(src+8);
            if(sec==2){ if(half==0){ er0=a0; er1=a1; } else { er2=a0; er3=a1; } }
            const u16* wsrc=Wep+(size_t)bn*384+sn*64+bk;
            b0=*(const u16x8*)wsrc; b1=*(const u16x8*)(wsrc+8);
        }
        __syncthreads();
        __builtin_amdgcn_s_setprio(1);
        const int arow=w*16+lr;
#pragma unroll
        for(int kk=0;kk<64;kk+=32){
            s8v a=*(const s8v*)&As[buf][arow*68+kk+kg*8];
#pragma unroll
            for(int ct=0;ct<8;++ct){
                s8v bfr=*(const s8v*)&Bs[buf][(ct*16+lr)*68+kk+kg*8];
                acc[ct]=__builtin_amdgcn_mfma_f32_16x16x32_bf16(a,bfr,acc[ct],0,0,0);
            }
        }
        __builtin_amdgcn_s_setprio(0);
    }
    float sum[4]={0.f,0.f,0.f,0.f}, sq[4]={0.f,0.f,0.f,0.f};
#pragma unroll
    for(int ct=0;ct<8;++ct){
        float bev=be[ct*16+lr];
#pragma unroll
        for(int reg=0;reg<4;++reg){
            float v=acc[ct][reg]+bev;
            acc[ct][reg]=v;
            sum[reg]+=v; sq[reg]+=v*v;
        }
    }
#pragma unroll
    for(int m=1;m<16;m<<=1){
#pragma unroll
        for(int reg=0;reg<4;++reg){
            sum[reg]+=__shfl_xor(sum[reg],m,64);
            sq[reg] +=__shfl_xor(sq[reg], m,64);
        }
    }
    float mean[4], rstd[4];
#pragma unroll
    for(int reg=0;reg<4;++reg){
        mean[reg]=sum[reg]*(1.f/128.f);
        float var=sq[reg]*(1.f/128.f)-mean[reg]*mean[reg];
        rstd[reg]=rsqrtf(var+1e-5f);
    }
    __syncthreads();
    u16* ep=&Bs[0][0];
#pragma unroll
    for(int ct=0;ct<8;++ct){
        int col=ct*16+lr;
        float gv=g[col], bv=b[col];
#pragma unroll
        for(int reg=0;reg<4;++reg){
            float hh=gv*(acc[ct][reg]-mean[reg])*rstd[reg]+bv;
            ep[(w*16+kg*4+reg)*EPS_+col]=f2b(silu_f(hh));
        }
    }
    {
        int eid=row0+ar;
        if(eid<Ne){
            u16* erow=e+(size_t)eid*128;
            const u16* hr=&ep[ar*EPS_];
            u16x8 h0=*(const u16x8*)(hr+ac),    h1=*(const u16x8*)(hr+ac+8);
            u16x8 h2=*(const u16x8*)(hr+64+ac), h3=*(const u16x8*)(hr+64+ac+8);
            u16x8 o0,o1,o2,o3;
#pragma unroll
            for(int j=0;j<8;++j){
                o0[j]=f2b(b2f(er0[j])+b2f(h0[j]));
                o1[j]=f2b(b2f(er1[j])+b2f(h1[j]));
                o2[j]=f2b(b2f(er2[j])+b2f(h2[j]));
                o3[j]=f2b(b2f(er3[j])+b2f(h3[j]));
            }
            *(u16x8*)(erow+ac)=o0;    *(u16x8*)(erow+ac+8)=o1;
            *(u16x8*)(erow+64+ac)=o2; *(u16x8*)(erow+64+ac+8)=o3;
        }
    }
}

// ---------------- BatchNorm / pool / head --------------------------------------
__global__ __launch_bounds__(256)
void bn_stats_k(const u16* __restrict__ h, float* __restrict__ st, int N){
    int t=blockIdx.x*256+threadIdx.x;
    int d=t&127, r0=t>>7, rstride=(gridDim.x*256)>>7;
    float s=0.f,q=0.f;
    for(int r=r0;r<N;r+=rstride){ float v=b2f(h[(size_t)r*128+d]); s+=v; q+=v*v; }
    atomicAdd(&st[d],s); atomicAdd(&st[128+d],q);
}
__global__ __launch_bounds__(256)
void bn_apply_k(u16* __restrict__ h, const float* __restrict__ st,
                const float* __restrict__ g, const float* __restrict__ b, int N){
    int t=blockIdx.x*256+threadIdx.x;
    if(t>=N*128) return;
    int d=t&127;
    float inv=1.f/(float)N;
    float m=st[d]*inv, var=st[128+d]*inv-m*m;
    float v=g[d]*(b2f(h[t])-m)*rsqrtf(var+1e-5f)+b[d];
    h[t]=f2b(silu_f(v));
}
__global__ __launch_bounds__(256)
void pool_k(const u16* __restrict__ o, const int* __restrict__ batch,
            const int* __restrict__ iflag,
            float* __restrict__ pooled, float* __restrict__ cnt, int N, int NG){
    int st=iflag[2];
    int wid=threadIdx.x>>6, lane=threadIdx.x&63;
    int n=blockIdx.x*4+wid; if(n>=N) return;
    int gi=batch[(size_t)n*st]; gi=gi<0?0:(gi>=NG?NG-1:gi);
    atomicAdd(&pooled[(size_t)gi*128+lane],    b2f(o[(size_t)n*128+lane]));
    atomicAdd(&pooled[(size_t)gi*128+64+lane], b2f(o[(size_t)n*128+64+lane]));
    if(lane==0) atomicAdd(&cnt[gi],1.f);
}
__global__ void final_k(const float* __restrict__ pooled, const float* __restrict__ cnt,
                        const float* __restrict__ oW, const float* __restrict__ ob,
                        float* __restrict__ out){
    int gi=blockIdx.x, lane=threadIdx.x;
    float v=pooled[(size_t)gi*128+lane]*oW[lane]
           +pooled[(size_t)gi*128+64+lane]*oW[64+lane];
    for(int m=32;m;m>>=1) v+=__shfl_xor(v,m,64);
    if(lane==0) out[gi]=v/fmaxf(cnt[gi],1.f)+ob[0];
}

// -------------------------------------------------------------------------------
template<typename TA>
static inline void gemm(hipStream_t s, const TA* A, int lda, int M, int K, int Kp,
                        const u16* Wp, const float* bias, u16* C, int act){
    dim3 grid((M+63)/64);
    if(act) gemm_k<TA,1><<<grid,256,0,s>>>(A,lda,M,K,Kp,Wp,bias,C);
    else    gemm_k<TA,0><<<grid,256,0,s>>>(A,lda,M,K,Kp,Wp,bias,C);
}

static inline void build_csr(hipStream_t s, const int* idx, int fi, long joff, const int* iflag,
                             int Ne, int Nn, int* off, int* cur, int* list, int* jlist, int* tot){
    int nb=(Nn+SCH-1)/SCH;
    zero_i_k<<<256,256,0,s>>>(cur,Nn);
    hist_k<<<(Ne+255)/256,256,0,s>>>(idx,iflag,fi,cur,Ne,Nn);
    scan1_k<<<nb,256,0,s>>>(cur,tot,Nn);
    scan2_k<<<1,1,0,s>>>(tot,nb);
    scan3_k<<<nb,256,0,s>>>(cur,tot,off,Nn,Ne);
    zero_i_k<<<256,256,0,s>>>(cur,Nn);
    fill_k<<<(Ne+255)/256,256,0,s>>>(idx,iflag,fi,joff,off,cur,list,jlist,Ne,Nn);
}

static inline void pack_w(hipStream_t s, const float* W, u16* Wp, int K, int Kp){
    pack_w_k<<<(128*Kp+255)/256,256,0,s>>>(W,Wp,K,Kp);
}

extern "C" void kernel_launch(void* const* d_in, const int* in_sizes, int n_in,
                              void* d_out, int out_size, void* d_ws, size_t ws_size,
                              hipStream_t stream)
{
    const float* x_in =(const float*)d_in[0];
    const float* ea   =(const float*)d_in[1];
    const float* eal  =(const float*)d_in[2];
    const int*   ei   =(const int*)d_in[3];
    const int*   eil  =(const int*)d_in[4];
    const int*   batch=(const int*)d_in[5];
    const float* pre1W=(const float*)d_in[6];  const float* pre1b=(const float*)d_in[7];
    const float* pre2W=(const float*)d_in[8];  const float* pre2b=(const float*)d_in[9];
    const float* pre3W=(const float*)d_in[10]; const float* pre3b=(const float*)d_in[11];
    const float* lWsrc=(const float*)d_in[12]; const float* lbsrc=(const float*)d_in[13];
    const float* lWdst=(const float*)d_in[14]; const float* lbdst=(const float*)d_in[15];
    const float* lWe  =(const float*)d_in[16]; const float* lbe  =(const float*)d_in[17];
    const float* lnxg =(const float*)d_in[18]; const float* lnxb =(const float*)d_in[19];
    const float* lneg =(const float*)d_in[20]; const float* lneb =(const float*)d_in[21];
    const float* aWsrc=(const float*)d_in[22]; const float* absrc=(const float*)d_in[23];
    const float* aWdst=(const float*)d_in[24]; const float* abdst=(const float*)d_in[25];
    const float* aWe  =(const float*)d_in[26]; const float* abe  =(const float*)d_in[27];
    const float* anxg =(const float*)d_in[28]; const float* anxb =(const float*)d_in[29];
    const float* aneg =(const float*)d_in[30]; const float* aneb =(const float*)d_in[31];
    const float* bng  =(const float*)d_in[32]; const float* bnb  =(const float*)d_in[33];
    const float* postW=(const float*)d_in[34]; const float* postb=(const float*)d_in[35];
    const float* outW =(const float*)d_in[36]; const float* outb =(const float*)d_in[37];
    (void)n_in;

    const int N =in_sizes[5];
    const int E =in_sizes[3]/2;
    const int EL=in_sizes[4]/2;
    const int NG=out_size;
    const int CH=(E+1)/2;

    char* base=(char*)d_ws;
    size_t off=0;
    auto alloc=[&](size_t bytes)->char*{
        char* p=base+off; off=(off+bytes+255)&~(size_t)255; return p;
    };
    u16* hNa  =(u16*)alloc((size_t)N*128*2);
    u16* hNb  =(u16*)alloc((size_t)N*128*2);
    u16* hEa  =(u16*)alloc((size_t)E*128*2);
    u16* hEb  =(u16*)alloc((size_t)E*128*2);   // alt buffer (raw partial + x_new)
    u16* hL   =(u16*)alloc((size_t)EL*128*2);
    u16* P1   =(u16*)alloc((size_t)CH*128*2);  // also post-FC output
    int* off_l=(int*)alloc((size_t)(E+1)*4);
    int* cur_l=(int*)alloc((size_t)E*4);
    int* list_l=(int*)alloc((size_t)EL*4);
    int* jlist_l=(int*)alloc((size_t)EL*4);
    int* off_a=(int*)alloc((size_t)(N+1)*4);
    int* cur_a=(int*)alloc((size_t)N*4);
    int* list_a=(int*)alloc((size_t)E*4);
    int* jlist_a=(int*)alloc((size_t)E*4);
    int* tot  =(int*)alloc(4096);
    int* iflag=(int*)alloc(64);
    float* stats =(float*)alloc(256*4);
    float* pooled=(float*)alloc((size_t)NG*128*4);
    float* cnt   =(float*)alloc((size_t)NG*4);
    u16* pre1p=(u16*)alloc(128*128*2);
    u16* pre2p=(u16*)alloc(128*64*2);
    u16* pre3p=(u16*)alloc(128*64*2);
    u16* postp=(u16*)alloc(128*128*2);
    u16 *lsrcp[4],*ldstp[4],*lWep[4],*asrcp[4],*adstp[4],*aWep[4];
    for(int i=0;i<4;i++){
        lsrcp[i]=(u16*)alloc(128*128*2);
        ldstp[i]=(u16*)alloc(128*128*2);
        lWep[i] =(u16*)alloc(128*384*2);
        asrcp[i]=(u16*)alloc(128*128*2);
        adstp[i]=(u16*)alloc(128*128*2);
        aWep[i] =(u16*)alloc(128*384*2);
    }
    if(off>ws_size){
        diag_k<<<(NG+255)/256,256,0,stream>>>((float*)d_out,NG,(float)(ws_size>>20)+0.25f);
        return;
    }

    probe_k<<<1,64,0,stream>>>(ei,eil,batch,N,iflag);
    build_csr(stream,eil,1,EL,iflag,EL,E,off_l,cur_l,list_l,jlist_l,tot);
    build_csr(stream,ei, 0,E, iflag,E, N,off_a,cur_a,list_a,jlist_a,tot);

    pack_w(stream,pre1W,pre1p,92,128);
    pack_w(stream,pre2W,pre2p,50,64);
    pack_w(stream,pre3W,pre3p,40,64);
    pack_w(stream,postW,postp,128,128);
    for(int i=0;i<4;i++){
        pack_w(stream,lWsrc+(size_t)i*128*128,lsrcp[i],128,128);
        pack_w(stream,lWdst+(size_t)i*128*128,ldstp[i],128,128);
        pack_w(stream,lWe  +(size_t)i*384*128,lWep[i],384,384);
        pack_w(stream,aWsrc+(size_t)i*128*128,asrcp[i],128,128);
        pack_w(stream,aWdst+(size_t)i*128*128,adstp[i],128,128);
        pack_w(stream,aWe  +(size_t)i*384*128,aWep[i],384,384);
    }

    u16* hN=hNa; u16* hNalt=hNb;
    u16* hE=hEa; u16* hEalt=hEb;

    gemm(stream,x_in,92,N, 92,128,pre1p,pre1b,hN,1);
    gemm(stream,ea,  50,E, 50, 64,pre2p,pre2b,hE,1);
    gemm(stream,eal, 40,EL,40, 64,pre3p,pre3b,hL,1);

    for(int l=0;l<NCONV_DEF;++l){
        {   // ===== line conv: nodes=hE (E), edges=hL (EL) =====
            gemm(stream,hE,128,CH,128,128,ldstp[l],lbdst+l*128,P1,0);
            gatherp_k<<<(E+7)/8,256,0,stream>>>(hL,P1,hEalt,off_l,list_l,jlist_l,E,0,CH);
            gemm(stream,hE+(size_t)CH*128,128,E-CH,128,128,ldstp[l],lbdst+l*128,P1,0);
            gatherz_k<1><<<(E+63)/64,256,0,stream>>>(hE,hEalt,hL,P1,off_l,list_l,jlist_l,
                                                     lsrcp[l],lbsrc+l*128,
                                                     lnxg+l*128,lnxb+l*128,E,CH,E);
            edgez_k<<<(EL+127)/128,512,0,stream>>>(hL,hE,eil,EL,iflag,1,
                                                   lWep[l],lbe+l*128,lneg+l*128,lneb+l*128,EL,E);
            u16* t=hE; hE=hEalt; hEalt=t;
        }
        {   // ===== atom conv: nodes=hN (N), edges=hE (E) =====
            gemm(stream,hN,128,N,128,128,adstp[l],abdst+l*128,P1,0);
            gatherz_k<0><<<(N+63)/64,256,0,stream>>>(hN,hNalt,hE,P1,off_a,list_a,jlist_a,
                                                     asrcp[l],absrc+l*128,
                                                     anxg+l*128,anxb+l*128,N,0,N);
            edgez_k<<<(E+127)/128,512,0,stream>>>(hE,hN,ei,E,iflag,0,
                                                  aWep[l],abe+l*128,aneg+l*128,aneb+l*128,E,N);
            u16* t=hN; hN=hNalt; hNalt=t;
        }
    }

    zero_f_k<<<64,256,0,stream>>>(stats,256);
    zero_f_k<<<64,256,0,stream>>>(pooled,(long)NG*128);
    zero_f_k<<<1,256,0,stream>>>(cnt,NG);
    bn_stats_k<<<256,256,0,stream>>>(hN,stats,N);
    bn_apply_k<<<(N*128+255)/256,256,0,stream>>>(hN,stats,bng,bnb,N);

    gemm(stream,hN,128,N,128,128,postp,postb,P1,1);

    pool_k<<<(N+3)/4,256,0,stream>>>(P1,batch,iflag,pooled,cnt,N,NG);
    final_k<<<NG,64,0,stream>>>(pooled,cnt,outW,outb,(float*)d_out);
}

// Round 13
// 3172.145 us; speedup vs baseline: 1.2294x; 1.2294x over previous
//
#include <hip/hip_runtime.h>

#define NCONV_DEF 4
#define SCH 1024

typedef unsigned short u16;
typedef __attribute__((ext_vector_type(8))) short s8v;      // MFMA bf16 A/B frag
typedef __attribute__((ext_vector_type(4))) float f4v;      // MFMA C/D frag
typedef __attribute__((ext_vector_type(8))) unsigned short u16x8;

__device__ __forceinline__ float sigm_f(float x){ return 1.f/(1.f+__expf(-x)); }
__device__ __forceinline__ float silu_f(float x){ return x/(1.f+__expf(-x)); }
__device__ __forceinline__ float b2f(u16 h){ union{unsigned u; float f;} v; v.u=(unsigned)h<<16; return v.f; }
__device__ __forceinline__ u16 f2b(float f){ union{float f; unsigned u;} v; v.f=f; unsigned r=v.u+0x7fffu+((v.u>>16)&1u); return (u16)(r>>16); }
__device__ __forceinline__ float ldAv(const float* p, size_t i){ return p[i]; }
__device__ __forceinline__ float ldAv(const u16* p, size_t i){ return b2f(p[i]); }

#define EPS_ 136   // epilogue LDS row stride in u16 (272B)

__global__ __launch_bounds__(256) void zero_f_k(float* p, long n){
    long i=(long)blockIdx.x*256+threadIdx.x, st=(long)gridDim.x*256;
    for(;i<n;i+=st) p[i]=0.f;
}
__global__ __launch_bounds__(256) void zero_i_k(int* p, long n){
    long i=(long)blockIdx.x*256+threadIdx.x, st=(long)gridDim.x*256;
    for(;i<n;i+=st) p[i]=0;
}
__global__ void diag_k(float* out, int n, float v){
    int i=blockIdx.x*256+threadIdx.x; if(i<n) out[i]=v;
}
__global__ void probe_k(const int* ei, const int* eil, const int* batch, int nb, int* flag){
    if(threadIdx.x||blockIdx.x) return;
    int a=2,b=2,c=2;
    for(int k=0;k<64;k++){ if(ei[2*k+1]!=0) a=1; if(eil[2*k+1]!=0) b=1; }
    int base=nb-128;
    for(int k=0;k<64;k++){ if(batch[base+2*k+1]!=0) c=1; }
    flag[0]=a; flag[1]=b; flag[2]=c;
}

// ---------------- CSR build ----------------------------------------------------
__global__ __launch_bounds__(256)
void hist_k(const int* __restrict__ idx, const int* __restrict__ iflag, int fi,
            int* __restrict__ cnt, int Ne, int Nn){
    int e=blockIdx.x*256+threadIdx.x; if(e>=Ne) return;
    int st=iflag[fi];
    int i=idx[(size_t)e*st]; i=i<0?0:(i>=Nn?Nn-1:i);
    atomicAdd(&cnt[i],1);
}
__global__ __launch_bounds__(256)
void scan1_k(const int* cnt, int* tot, int n){
    __shared__ int sh[256];
    int base=blockIdx.x*SCH, s=0;
    for(int t=threadIdx.x;t<SCH;t+=256){ int i=base+t; s+=(i<n)?cnt[i]:0; }
    sh[threadIdx.x]=s; __syncthreads();
    for(int o=128;o;o>>=1){ if(threadIdx.x<o) sh[threadIdx.x]+=sh[threadIdx.x+o]; __syncthreads(); }
    if(threadIdx.x==0) tot[blockIdx.x]=sh[0];
}
__global__ void scan2_k(int* tot, int nb){
    if(threadIdx.x==0&&blockIdx.x==0){ int acc=0; for(int i=0;i<nb;i++){int v=tot[i]; tot[i]=acc; acc+=v;} }
}
__global__ __launch_bounds__(256)
void scan3_k(const int* cnt, const int* tot, int* off, int n, int total){
    __shared__ int sh[256];
    int b=blockIdx.x, t4=b*SCH+threadIdx.x*4;
    int v0=(t4+0<n)?cnt[t4+0]:0, v1=(t4+1<n)?cnt[t4+1]:0;
    int v2=(t4+2<n)?cnt[t4+2]:0, v3=(t4+3<n)?cnt[t4+3]:0;
    int ls=v0+v1+v2+v3;
    sh[threadIdx.x]=ls; __syncthreads();
    for(int o=1;o<256;o<<=1){
        int val=(threadIdx.x>=o)?sh[threadIdx.x-o]:0; __syncthreads();
        sh[threadIdx.x]+=val; __syncthreads();
    }
    int excl=sh[threadIdx.x]-ls+tot[b];
    if(t4+0<n) off[t4+0]=excl;
    if(t4+1<n) off[t4+1]=excl+v0;
    if(t4+2<n) off[t4+2]=excl+v0+v1;
    if(t4+3<n) off[t4+3]=excl+v0+v1+v2;
    if(b==(int)gridDim.x-1&&threadIdx.x==255) off[n]=total;
}
__global__ __launch_bounds__(256)
void fill_k(const int* __restrict__ idx, const int* __restrict__ iflag, int fi, long joff,
            const int* __restrict__ off, int* __restrict__ cur,
            int* __restrict__ list, int* __restrict__ jlist, int Ne, int Nn){
    int e=blockIdx.x*256+threadIdx.x; if(e>=Ne) return;
    int st=iflag[fi];
    int i=idx[(size_t)e*st]; i=i<0?0:(i>=Nn?Nn-1:i);
    int j=idx[((size_t)joff+e)*st]; j=j<0?0:(j>=Nn?Nn-1:j);
    int pos=off[i]+atomicAdd(&cur[i],1);
    list[pos]=e; jlist[pos]=j;
}

// ---------------- weight pack: W[K][128] f32 -> Wp[128][Kp] bf16 ---------------
__global__ __launch_bounds__(256)
void pack_w_k(const float* __restrict__ W, u16* __restrict__ Wp, int K, int Kp){
    int i=blockIdx.x*256+threadIdx.x;
    if(i>=128*Kp) return;
    int n=i/Kp, k=i-n*Kp;
    Wp[i] = (k<K) ? f2b(W[(size_t)k*128+n]) : (u16)0;
}

// ---------------- MFMA GEMM: C[M,128] = A[M,K] @ W[K,128] (+bias)(+silu) -------
template<typename TA, int ACT>
__global__ __launch_bounds__(256)
void gemm_k(const TA* __restrict__ A, int lda, int M, int K, int Kp,
            const u16* __restrict__ Wp, const float* __restrict__ bias,
            u16* __restrict__ C)
{
    __shared__ __align__(16) u16 As[64*72];
    __shared__ __align__(16) u16 Bs[128*72];
    const int tid=threadIdx.x, row0=blockIdx.x*64;
    const int w=tid>>6, l=tid&63, lr=l&15, kg=l>>4;
    f4v zz={0.f,0.f,0.f,0.f};
    f4v acc[8];
#pragma unroll
    for(int i=0;i<8;++i) acc[i]=zz;

    for(int kt=0;kt<Kp;kt+=64){
        {
            int r=tid>>2, c0=(tid&3)*16;
            int gr=row0+r;
            bool vec=false;
            if constexpr (sizeof(TA)==2) vec=((K&63)==0);
            if(vec){
                const u16* src=(const u16*)(const void*)A+(size_t)gr*lda+kt+c0;
                u16x8 v0={0,0,0,0,0,0,0,0}, v1={0,0,0,0,0,0,0,0};
                if(gr<M){ v0=*(const u16x8*)src; v1=*(const u16x8*)(src+8); }
                *(u16x8*)&As[r*72+c0]=v0;
                *(u16x8*)&As[r*72+c0+8]=v1;
            } else {
                for(int c=c0;c<c0+16;++c){
                    int k=kt+c;
                    float v=(gr<M&&k<K)?ldAv(A,(size_t)gr*lda+k):0.f;
                    As[r*72+c]=f2b(v);
                }
            }
        }
        {
            int n=tid>>1, k0=(tid&1)*32;
            const u16* src=Wp+(size_t)n*Kp+kt+k0;
            *(u16x8*)&Bs[n*72+k0]   =*(const u16x8*)(src);
            *(u16x8*)&Bs[n*72+k0+8] =*(const u16x8*)(src+8);
            *(u16x8*)&Bs[n*72+k0+16]=*(const u16x8*)(src+16);
            *(u16x8*)&Bs[n*72+k0+24]=*(const u16x8*)(src+24);
        }
        __syncthreads();
        const int arow=w*16+lr;
#pragma unroll
        for(int kk=0;kk<64;kk+=32){
            s8v a=*(const s8v*)&As[arow*72+kk+kg*8];
#pragma unroll
            for(int ct=0;ct<8;++ct){
                s8v bfr=*(const s8v*)&Bs[(ct*16+lr)*72+kk+kg*8];
                acc[ct]=__builtin_amdgcn_mfma_f32_16x16x32_bf16(a,bfr,acc[ct],0,0,0);
            }
        }
        __syncthreads();
    }
    u16* ep=Bs;
#pragma unroll
    for(int ct=0;ct<8;++ct){
        int col=ct*16+lr;
        float bv=bias?bias[col]:0.f;
#pragma unroll
        for(int reg=0;reg<4;++reg){
            float v=acc[ct][reg]+bv;
            if(ACT) v=silu_f(v);
            ep[(w*16+kg*4+reg)*EPS_+col]=f2b(v);
        }
    }
    __syncthreads();
    {
        int ar=tid>>2, gr=row0+ar;
        if(gr<M){
            u16* crow=C+(size_t)gr*128+(tid&3)*32;
            const u16* hrow=&ep[ar*EPS_+(tid&3)*32];
#pragma unroll
            for(int c4=0;c4<4;++c4)
                *(u16x8*)(crow+c4*8)=*(const u16x8*)(hrow+c4*8);
        }
    }
}

// ---------------- fused node update GEMM (IN PLACE on X) -----------------------
// X = X + silu(LN(X@Wsrc + bias + U))
__global__ __launch_bounds__(256)
void gemmz_k(u16* __restrict__ X, int M,
             const u16* __restrict__ Wp, const float* __restrict__ bias,
             const u16* __restrict__ U,
             const float* __restrict__ g, const float* __restrict__ b)
{
    __shared__ __align__(16) u16 As[2][64*68];
    __shared__ __align__(16) u16 Bs[128*136];
    const int tid=threadIdx.x, row0=blockIdx.x*64;
    const int w=tid>>6, l=tid&63, lr=l&15, kg=l>>4;
    u16* ep=&As[0][0];
    const int ar=tid>>2, gr=row0+ar;
    {
        u16x8 z8={0,0,0,0,0,0,0,0};
        u16x8 u0=z8,u1=z8,u2=z8,u3=z8;
        if(gr<M){
            const u16* ur=U+(size_t)gr*128+(tid&3)*32;
            u0=*(const u16x8*)(ur); u1=*(const u16x8*)(ur+8);
            u2=*(const u16x8*)(ur+16); u3=*(const u16x8*)(ur+24);
        }
        u16* d=&ep[ar*EPS_+(tid&3)*32];
        *(u16x8*)(d)=u0; *(u16x8*)(d+8)=u1; *(u16x8*)(d+16)=u2; *(u16x8*)(d+24)=u3;
    }
    __syncthreads();
    f4v acc[8];
#pragma unroll
    for(int ct=0;ct<8;++ct){
        int col=ct*16+lr;
        float bv=bias[col];
#pragma unroll
        for(int reg=0;reg<4;++reg)
            acc[ct][reg]=b2f(ep[(w*16+kg*4+reg)*EPS_+col])+bv;
    }
    __syncthreads();

    {
        int c0=(tid&3)*16;
        const u16* src=X+(size_t)gr*128;
        u16x8 z8={0,0,0,0,0,0,0,0};
        u16x8 v0=z8,v1=z8,v2=z8,v3=z8;
        if(gr<M){
            v0=*(const u16x8*)(src+c0);    v1=*(const u16x8*)(src+c0+8);
            v2=*(const u16x8*)(src+64+c0); v3=*(const u16x8*)(src+64+c0+8);
        }
        *(u16x8*)&As[0][ar*68+c0]=v0;  *(u16x8*)&As[0][ar*68+c0+8]=v1;
        *(u16x8*)&As[1][ar*68+c0]=v2;  *(u16x8*)&As[1][ar*68+c0+8]=v3;
        int bn=tid>>1, bk=(tid&1)*64;
        const u16* wsrc=Wp+(size_t)bn*128+bk;
#pragma unroll
        for(int q=0;q<8;++q)
            *(u16x8*)&Bs[bn*136+bk+q*8]=*(const u16x8*)(wsrc+q*8);
    }
    __syncthreads();
    const int arow=w*16+lr;
#pragma unroll
    for(int kt=0;kt<2;++kt){
#pragma unroll
        for(int kk=0;kk<64;kk+=32){
            s8v a=*(const s8v*)&As[kt][arow*68+kk+kg*8];
#pragma unroll
            for(int ct=0;ct<8;++ct){
                s8v bfr=*(const s8v*)&Bs[(ct*16+lr)*136+kt*64+kk+kg*8];
                acc[ct]=__builtin_amdgcn_mfma_f32_16x16x32_bf16(a,bfr,acc[ct],0,0,0);
            }
        }
    }
    float sum[4]={0.f,0.f,0.f,0.f}, sq[4]={0.f,0.f,0.f,0.f};
#pragma unroll
    for(int ct=0;ct<8;++ct)
#pragma unroll
        for(int reg=0;reg<4;++reg){
            float v=acc[ct][reg];
            sum[reg]+=v; sq[reg]+=v*v;
        }
#pragma unroll
    for(int m=1;m<16;m<<=1)
#pragma unroll
        for(int reg=0;reg<4;++reg){
            sum[reg]+=__shfl_xor(sum[reg],m,64);
            sq[reg] +=__shfl_xor(sq[reg], m,64);
        }
    float mean[4], rstd[4];
#pragma unroll
    for(int reg=0;reg<4;++reg){
        mean[reg]=sum[reg]*(1.f/128.f);
        float var=sq[reg]*(1.f/128.f)-mean[reg]*mean[reg];
        rstd[reg]=rsqrtf(var+1e-5f);
    }
    __syncthreads();
#pragma unroll
    for(int ct=0;ct<8;++ct){
        int col=ct*16+lr;
        float gv=g[col], bv=b[col];
#pragma unroll
        for(int reg=0;reg<4;++reg){
            float h=gv*(acc[ct][reg]-mean[reg])*rstd[reg]+bv;
            ep[(w*16+kg*4+reg)*EPS_+col]=f2b(silu_f(h));
        }
    }
    if(gr<M){
        u16* xrow=X+(size_t)gr*128+(tid&3)*32;
        const u16* hrow=&ep[ar*EPS_+(tid&3)*32];
#pragma unroll
        for(int c4=0;c4<4;++c4){
            u16x8 xv=*(const u16x8*)(xrow+c4*8);
            u16x8 hv=*(const u16x8*)(hrow+c4*8);
            u16x8 ov;
#pragma unroll
            for(int j=0;j<8;++j) ov[j]=f2b(b2f(xv[j])+b2f(hv[j]));
            *(u16x8*)(xrow+c4*8)=ov;
        }
    }
}

// ---------------- fused CSR gather v2: 2 nodes/wave, uint2, prefetch -----------
template<int FIN, int HASPREV>
__global__ __launch_bounds__(256)
void gather_k(const u16* __restrict__ e, const u16* __restrict__ P1,
              u16* __restrict__ U,
              const int* __restrict__ off, const int* __restrict__ list,
              const int* __restrict__ jlist,
              int Nn, int c0, int c1)
{
    int wid=threadIdx.x>>6, lane=threadIdx.x&63;
    int h=lane>>5, sl=lane&31;
    int n=blockIdx.x*8+wid*2+h;
    int beg=0,end=0;
    if(n<Nn){ beg=off[n]; end=off[n+1]; }
    const int d4=sl*4;
    uint2 uprev; uprev.x=0; uprev.y=0;
    if(FIN&&HASPREV&&n<Nn) uprev=*(const uint2*)(U+(size_t)n*128+d4);

    float es[4]={0.f,0.f,0.f,0.f}, a[4]={0.f,0.f,0.f,0.f};
    int k=beg;
    uint2 ev_n, pv_n; ev_n.x=ev_n.y=0; pv_n.x=pv_n.y=0;
    bool in_n=false;
    if(k<end){
        int eid=list[k], j=jlist[k];
        in_n=(j>=c0)&&(j<c1);
        if(FIN||in_n) ev_n=*(const uint2*)(e+(size_t)eid*128+d4);
        if(in_n)      pv_n=*(const uint2*)(P1+(size_t)(j-c0)*128+d4);
    }
    while(k<end){
        uint2 ev=ev_n, pv=pv_n; bool in=in_n;
        int kn=k+1;
        if(kn<end){
            int eid=list[kn], j=jlist[kn];
            in_n=(j>=c0)&&(j<c1);
            ev_n.x=ev_n.y=0; pv_n.x=pv_n.y=0;
            if(FIN||in_n) ev_n=*(const uint2*)(e+(size_t)eid*128+d4);
            if(in_n)      pv_n=*(const uint2*)(P1+(size_t)(j-c0)*128+d4);
        }
        float s0=sigm_f(b2f((u16)(ev.x&0xffff)));
        float s1=sigm_f(b2f((u16)(ev.x>>16)));
        float s2=sigm_f(b2f((u16)(ev.y&0xffff)));
        float s3=sigm_f(b2f((u16)(ev.y>>16)));
        if(FIN){ es[0]+=s0; es[1]+=s1; es[2]+=s2; es[3]+=s3; }
        if(in){
            a[0]+=s0*b2f((u16)(pv.x&0xffff));
            a[1]+=s1*b2f((u16)(pv.x>>16));
            a[2]+=s2*b2f((u16)(pv.y&0xffff));
            a[3]+=s3*b2f((u16)(pv.y>>16));
        }
        k=kn;
    }
    if(n>=Nn) return;
    uint2* up=(uint2*)(U+(size_t)n*128+d4);
    uint2 o;
    if(!FIN){
        o.x=((unsigned)f2b(a[0]))|((unsigned)f2b(a[1])<<16);
        o.y=((unsigned)f2b(a[2]))|((unsigned)f2b(a[3])<<16);
    } else {
        if(HASPREV){
            a[0]+=b2f((u16)(uprev.x&0xffff));
            a[1]+=b2f((u16)(uprev.x>>16));
            a[2]+=b2f((u16)(uprev.y&0xffff));
            a[3]+=b2f((u16)(uprev.y>>16));
        }
        float r0=1.f/(es[0]+1e-5f), r1=1.f/(es[1]+1e-5f);
        float r2=1.f/(es[2]+1e-5f), r3=1.f/(es[3]+1e-5f);
        o.x=((unsigned)f2b(a[0]*r0))|((unsigned)f2b(a[1]*r1)<<16);
        o.y=((unsigned)f2b(a[2]*r2))|((unsigned)f2b(a[3]*r3)<<16);
    }
    *up=o;
}

// ---------------- fused edge update v4: A direct-to-register, B-only LDS -------
// 128 edges/block, 512 threads. LDS = B dbuf (34.8 KB) + rid -> 3-4 blocks/CU.
__global__ __launch_bounds__(512)
void edgez_k(u16* __restrict__ e, const u16* __restrict__ x,
             const int* __restrict__ idx, long joff,
             const int* __restrict__ iflag, int fi,
             const u16* __restrict__ Wep, const float* __restrict__ be,
             const float* __restrict__ g, const float* __restrict__ b,
             int Ne, int Nn)
{
    __shared__ __align__(16) u16 Bs[2][128*68];    // 34816 B; whole region = ep
    __shared__ int rid[256];
    const int tid=threadIdx.x, row0=blockIdx.x*128;
    const int w=tid>>6, l=tid&63, lr=l&15, kg=l>>4;
    int st=iflag[fi];
    if(tid<256){
        int r=tid&127, eid=row0+r; if(eid>=Ne) eid=Ne-1;
        long elem=(tid<128)?(long)eid:(joff+eid);
        int v=idx[(size_t)elem*st]; v=v<0?0:(v>=Nn?Nn-1:v);
        rid[tid]=v;
    }
    __syncthreads();
    const int bn=tid>>2, bk=(tid&3)*16;
    const int mr=w*16+lr;                       // this lane's output row
    int eidM=row0+mr; if(eidM>=Ne) eidM=Ne-1;
    const u16* aA=x+(size_t)rid[mr]*128;        // x_i row
    const u16* aB=x+(size_t)rid[128+mr]*128;    // x_j row
    const u16* aC=e+(size_t)eidM*128;           // e row

    f4v zz={0.f,0.f,0.f,0.f};
    f4v acc[8];
#pragma unroll
    for(int i=0;i<8;++i) acc[i]=zz;

    s8v a0,a1,an0,an1;
    u16x8 b0,b1;
    {   // loads for s=0
        a0=*(const s8v*)(aA+kg*8);
        a1=*(const s8v*)(aA+32+kg*8);
        const u16* wsrc=Wep+(size_t)bn*384+bk;
        b0=*(const u16x8*)wsrc; b1=*(const u16x8*)(wsrc+8);
    }
#pragma unroll
    for(int s=0;s<6;++s){
        const int buf=s&1;
        *(u16x8*)&Bs[buf][bn*68+bk]  =b0;
        *(u16x8*)&Bs[buf][bn*68+bk+8]=b1;
        if(s<5){                         // prefetch s+1 (hidden under MFMA)
            const int sn=s+1, sec=sn>>1, half=sn&1;
            const u16* ap=(sec==0?aA:(sec==1?aB:aC))+half*64;
            an0=*(const s8v*)(ap+kg*8);
            an1=*(const s8v*)(ap+32+kg*8);
            const u16* wsrc=Wep+(size_t)bn*384+sn*64+bk;
            b0=*(const u16x8*)wsrc; b1=*(const u16x8*)(wsrc+8);
        }
        __syncthreads();
        __builtin_amdgcn_s_setprio(1);
#pragma unroll
        for(int ct=0;ct<8;++ct){
            s8v bfr=*(const s8v*)&Bs[buf][(ct*16+lr)*68+kg*8];
            acc[ct]=__builtin_amdgcn_mfma_f32_16x16x32_bf16(a0,bfr,acc[ct],0,0,0);
        }
#pragma unroll
        for(int ct=0;ct<8;++ct){
            s8v bfr=*(const s8v*)&Bs[buf][(ct*16+lr)*68+32+kg*8];
            acc[ct]=__builtin_amdgcn_mfma_f32_16x16x32_bf16(a1,bfr,acc[ct],0,0,0);
        }
        __builtin_amdgcn_s_setprio(0);
        a0=an0; a1=an1;
    }
    // LN stats (register-only)
    float sum[4]={0.f,0.f,0.f,0.f}, sq[4]={0.f,0.f,0.f,0.f};
#pragma unroll
    for(int ct=0;ct<8;++ct){
        float bev=be[ct*16+lr];
#pragma unroll
        for(int reg=0;reg<4;++reg){
            float v=acc[ct][reg]+bev;
            acc[ct][reg]=v;
            sum[reg]+=v; sq[reg]+=v*v;
        }
    }
#pragma unroll
    for(int m=1;m<16;m<<=1){
#pragma unroll
        for(int reg=0;reg<4;++reg){
            sum[reg]+=__shfl_xor(sum[reg],m,64);
            sq[reg] +=__shfl_xor(sq[reg], m,64);
        }
    }
    float mean[4], rstd[4];
#pragma unroll
    for(int reg=0;reg<4;++reg){
        mean[reg]=sum[reg]*(1.f/128.f);
        float var=sq[reg]*(1.f/128.f)-mean[reg]*mean[reg];
        rstd[reg]=rsqrtf(var+1e-5f);
    }
    __syncthreads();   // all MFMA(5) reads done before ep (whole Bs) overwrite
    u16* ep=&Bs[0][0];
#pragma unroll
    for(int ct=0;ct<8;++ct){
        int col=ct*16+lr;
        float gv=g[col], bv=b[col];
#pragma unroll
        for(int reg=0;reg<4;++reg){
            float hh=gv*(acc[ct][reg]-mean[reg])*rstd[reg]+bv;
            ep[(w*16+kg*4+reg)*EPS_+col]=f2b(silu_f(hh));
        }
    }
    // intra-wave ep read + e re-read (L1/L2 hot) -> coalesced store
    {
        const int ar=tid>>2, ac=(tid&3)*16;
        int eid=row0+ar;
        if(eid<Ne){
            u16* erow=e+(size_t)eid*128;
            const u16* hr=&ep[ar*EPS_];
            u16x8 e0=*(const u16x8*)(erow+ac),    e1=*(const u16x8*)(erow+ac+8);
            u16x8 e2=*(const u16x8*)(erow+64+ac), e3=*(const u16x8*)(erow+64+ac+8);
            u16x8 h0=*(const u16x8*)(hr+ac),    h1=*(const u16x8*)(hr+ac+8);
            u16x8 h2=*(const u16x8*)(hr+64+ac), h3=*(const u16x8*)(hr+64+ac+8);
            u16x8 o0,o1,o2,o3;
#pragma unroll
            for(int j=0;j<8;++j){
                o0[j]=f2b(b2f(e0[j])+b2f(h0[j]));
                o1[j]=f2b(b2f(e1[j])+b2f(h1[j]));
                o2[j]=f2b(b2f(e2[j])+b2f(h2[j]));
                o3[j]=f2b(b2f(e3[j])+b2f(h3[j]));
            }
            *(u16x8*)(erow+ac)=o0;    *(u16x8*)(erow+ac+8)=o1;
            *(u16x8*)(erow+64+ac)=o2; *(u16x8*)(erow+64+ac+8)=o3;
        }
    }
}

// ---------------- BatchNorm / pool / head --------------------------------------
__global__ __launch_bounds__(256)
void bn_stats_k(const u16* __restrict__ h, float* __restrict__ st, int N){
    int t=blockIdx.x*256+threadIdx.x;
    int d=t&127, r0=t>>7, rstride=(gridDim.x*256)>>7;
    float s=0.f,q=0.f;
    for(int r=r0;r<N;r+=rstride){ float v=b2f(h[(size_t)r*128+d]); s+=v; q+=v*v; }
    atomicAdd(&st[d],s); atomicAdd(&st[128+d],q);
}
__global__ __launch_bounds__(256)
void bn_apply_k(u16* __restrict__ h, const float* __restrict__ st,
                const float* __restrict__ g, const float* __restrict__ b, int N){
    int t=blockIdx.x*256+threadIdx.x;
    if(t>=N*128) return;
    int d=t&127;
    float inv=1.f/(float)N;
    float m=st[d]*inv, var=st[128+d]*inv-m*m;
    float v=g[d]*(b2f(h[t])-m)*rsqrtf(var+1e-5f)+b[d];
    h[t]=f2b(silu_f(v));
}
__global__ __launch_bounds__(256)
void pool_k(const u16* __restrict__ o, const int* __restrict__ batch,
            const int* __restrict__ iflag,
            float* __restrict__ pooled, float* __restrict__ cnt, int N, int NG){
    int st=iflag[2];
    int wid=threadIdx.x>>6, lane=threadIdx.x&63;
    int n=blockIdx.x*4+wid; if(n>=N) return;
    int gi=batch[(size_t)n*st]; gi=gi<0?0:(gi>=NG?NG-1:gi);
    atomicAdd(&pooled[(size_t)gi*128+lane],    b2f(o[(size_t)n*128+lane]));
    atomicAdd(&pooled[(size_t)gi*128+64+lane], b2f(o[(size_t)n*128+64+lane]));
    if(lane==0) atomicAdd(&cnt[gi],1.f);
}
__global__ void final_k(const float* __restrict__ pooled, const float* __restrict__ cnt,
                        const float* __restrict__ oW, const float* __restrict__ ob,
                        float* __restrict__ out){
    int gi=blockIdx.x, lane=threadIdx.x;
    float v=pooled[(size_t)gi*128+lane]*oW[lane]
           +pooled[(size_t)gi*128+64+lane]*oW[64+lane];
    for(int m=32;m;m>>=1) v+=__shfl_xor(v,m,64);
    if(lane==0) out[gi]=v/fmaxf(cnt[gi],1.f)+ob[0];
}

// -------------------------------------------------------------------------------
template<typename TA>
static inline void gemm(hipStream_t s, const TA* A, int lda, int M, int K, int Kp,
                        const u16* Wp, const float* bias, u16* C, int act){
    dim3 grid((M+63)/64);
    if(act) gemm_k<TA,1><<<grid,256,0,s>>>(A,lda,M,K,Kp,Wp,bias,C);
    else    gemm_k<TA,0><<<grid,256,0,s>>>(A,lda,M,K,Kp,Wp,bias,C);
}

static inline void build_csr(hipStream_t s, const int* idx, int fi, long joff, const int* iflag,
                             int Ne, int Nn, int* off, int* cur, int* list, int* jlist, int* tot){
    int nb=(Nn+SCH-1)/SCH;
    zero_i_k<<<256,256,0,s>>>(cur,Nn);
    hist_k<<<(Ne+255)/256,256,0,s>>>(idx,iflag,fi,cur,Ne,Nn);
    scan1_k<<<nb,256,0,s>>>(cur,tot,Nn);
    scan2_k<<<1,1,0,s>>>(tot,nb);
    scan3_k<<<nb,256,0,s>>>(cur,tot,off,Nn,Ne);
    zero_i_k<<<256,256,0,s>>>(cur,Nn);
    fill_k<<<(Ne+255)/256,256,0,s>>>(idx,iflag,fi,joff,off,cur,list,jlist,Ne,Nn);
}

static inline void pack_w(hipStream_t s, const float* W, u16* Wp, int K, int Kp){
    pack_w_k<<<(128*Kp+255)/256,256,0,s>>>(W,Wp,K,Kp);
}

extern "C" void kernel_launch(void* const* d_in, const int* in_sizes, int n_in,
                              void* d_out, int out_size, void* d_ws, size_t ws_size,
                              hipStream_t stream)
{
    const float* x_in =(const float*)d_in[0];
    const float* ea   =(const float*)d_in[1];
    const float* eal  =(const float*)d_in[2];
    const int*   ei   =(const int*)d_in[3];
    const int*   eil  =(const int*)d_in[4];
    const int*   batch=(const int*)d_in[5];
    const float* pre1W=(const float*)d_in[6];  const float* pre1b=(const float*)d_in[7];
    const float* pre2W=(const float*)d_in[8];  const float* pre2b=(const float*)d_in[9];
    const float* pre3W=(const float*)d_in[10]; const float* pre3b=(const float*)d_in[11];
    const float* lWsrc=(const float*)d_in[12]; const float* lbsrc=(const float*)d_in[13];
    const float* lWdst=(const float*)d_in[14]; const float* lbdst=(const float*)d_in[15];
    const float* lWe  =(const float*)d_in[16]; const float* lbe  =(const float*)d_in[17];
    const float* lnxg =(const float*)d_in[18]; const float* lnxb =(const float*)d_in[19];
    const float* lneg =(const float*)d_in[20]; const float* lneb =(const float*)d_in[21];
    const float* aWsrc=(const float*)d_in[22]; const float* absrc=(const float*)d_in[23];
    const float* aWdst=(const float*)d_in[24]; const float* abdst=(const float*)d_in[25];
    const float* aWe  =(const float*)d_in[26]; const float* abe  =(const float*)d_in[27];
    const float* anxg =(const float*)d_in[28]; const float* anxb =(const float*)d_in[29];
    const float* aneg =(const float*)d_in[30]; const float* aneb =(const float*)d_in[31];
    const float* bng  =(const float*)d_in[32]; const float* bnb  =(const float*)d_in[33];
    const float* postW=(const float*)d_in[34]; const float* postb=(const float*)d_in[35];
    const float* outW =(const float*)d_in[36]; const float* outb =(const float*)d_in[37];
    (void)n_in;

    const int N =in_sizes[5];
    const int E =in_sizes[3]/2;
    const int EL=in_sizes[4]/2;
    const int NG=out_size;
    const int CH=(E+1)/2;

    char* base=(char*)d_ws;
    size_t off=0;
    auto alloc=[&](size_t bytes)->char*{
        char* p=base+off; off=(off+bytes+255)&~(size_t)255; return p;
    };
    u16* hN   =(u16*)alloc((size_t)N*128*2);
    u16* hE   =(u16*)alloc((size_t)E*128*2);
    u16* hL   =(u16*)alloc((size_t)EL*128*2);
    u16* U    =(u16*)alloc((size_t)E*128*2);
    u16* P1   =(u16*)alloc((size_t)CH*128*2);
    int* off_l=(int*)alloc((size_t)(E+1)*4);
    int* cur_l=(int*)alloc((size_t)E*4);
    int* list_l=(int*)alloc((size_t)EL*4);
    int* jlist_l=(int*)alloc((size_t)EL*4);
    int* off_a=(int*)alloc((size_t)(N+1)*4);
    int* cur_a=(int*)alloc((size_t)N*4);
    int* list_a=(int*)alloc((size_t)E*4);
    int* jlist_a=(int*)alloc((size_t)E*4);
    int* tot  =(int*)alloc(4096);
    int* iflag=(int*)alloc(64);
    float* stats =(float*)alloc(256*4);
    float* pooled=(float*)alloc((size_t)NG*128*4);
    float* cnt   =(float*)alloc((size_t)NG*4);
    u16* pre1p=(u16*)alloc(128*128*2);
    u16* pre2p=(u16*)alloc(128*64*2);
    u16* pre3p=(u16*)alloc(128*64*2);
    u16* postp=(u16*)alloc(128*128*2);
    u16 *lsrcp[4],*ldstp[4],*lWep[4],*asrcp[4],*adstp[4],*aWep[4];
    for(int i=0;i<4;i++){
        lsrcp[i]=(u16*)alloc(128*128*2);
        ldstp[i]=(u16*)alloc(128*128*2);
        lWep[i] =(u16*)alloc(128*384*2);
        asrcp[i]=(u16*)alloc(128*128*2);
        adstp[i]=(u16*)alloc(128*128*2);
        aWep[i] =(u16*)alloc(128*384*2);
    }
    if(off>ws_size){
        diag_k<<<(NG+255)/256,256,0,stream>>>((float*)d_out,NG,(float)(ws_size>>20)+0.25f);
        return;
    }

    probe_k<<<1,64,0,stream>>>(ei,eil,batch,N,iflag);
    build_csr(stream,eil,1,EL,iflag,EL,E,off_l,cur_l,list_l,jlist_l,tot);
    build_csr(stream,ei, 0,E, iflag,E, N,off_a,cur_a,list_a,jlist_a,tot);

    pack_w(stream,pre1W,pre1p,92,128);
    pack_w(stream,pre2W,pre2p,50,64);
    pack_w(stream,pre3W,pre3p,40,64);
    pack_w(stream,postW,postp,128,128);
    for(int i=0;i<4;i++){
        pack_w(stream,lWsrc+(size_t)i*128*128,lsrcp[i],128,128);
        pack_w(stream,lWdst+(size_t)i*128*128,ldstp[i],128,128);
        pack_w(stream,lWe  +(size_t)i*384*128,lWep[i],384,384);
        pack_w(stream,aWsrc+(size_t)i*128*128,asrcp[i],128,128);
        pack_w(stream,aWdst+(size_t)i*128*128,adstp[i],128,128);
        pack_w(stream,aWe  +(size_t)i*384*128,aWep[i],384,384);
    }

    gemm(stream,x_in,92,N, 92,128,pre1p,pre1b,hN,1);
    gemm(stream,ea,  50,E, 50, 64,pre2p,pre2b,hE,1);
    gemm(stream,eal, 40,EL,40, 64,pre3p,pre3b,hL,1);

    for(int l=0;l<NCONV_DEF;++l){
        {   // ===== line conv: nodes=hE (E), edges=hL (EL) =====
            gemm(stream,hE,128,CH,128,128,ldstp[l],lbdst+l*128,P1,0);
            gather_k<0,0><<<(E+7)/8,256,0,stream>>>(hL,P1,U,off_l,list_l,jlist_l,E,0,CH);
            gemm(stream,hE+(size_t)CH*128,128,E-CH,128,128,ldstp[l],lbdst+l*128,P1,0);
            gather_k<1,1><<<(E+7)/8,256,0,stream>>>(hL,P1,U,off_l,list_l,jlist_l,E,CH,E);
            edgez_k<<<(EL+127)/128,512,0,stream>>>(hL,hE,eil,EL,iflag,1,
                                                   lWep[l],lbe+l*128,lneg+l*128,lneb+l*128,EL,E);
            gemmz_k<<<(E+63)/64,256,0,stream>>>(hE,E,lsrcp[l],lbsrc+l*128,U,
                                                lnxg+l*128,lnxb+l*128);
        }
        {   // ===== atom conv: nodes=hN (N), edges=hE (E) =====
            gemm(stream,hN,128,N,128,128,adstp[l],abdst+l*128,P1,0);
            gather_k<1,0><<<(N+7)/8,256,0,stream>>>(hE,P1,U,off_a,list_a,jlist_a,N,0,N);
            edgez_k<<<(E+127)/128,512,0,stream>>>(hE,hN,ei,E,iflag,0,
                                                  aWep[l],abe+l*128,aneg+l*128,aneb+l*128,E,N);
            gemmz_k<<<(N+63)/64,256,0,stream>>>(hN,N,asrcp[l],absrc+l*128,U,
                                                anxg+l*128,anxb+l*128);
        }
    }

    zero_f_k<<<64,256,0,stream>>>(stats,256);
    zero_f_k<<<64,256,0,stream>>>(pooled,(long)NG*128);
    zero_f_k<<<1,256,0,stream>>>(cnt,NG);
    bn_stats_k<<<256,256,0,stream>>>(hN,stats,N);
    bn_apply_k<<<(N*128+255)/256,256,0,stream>>>(hN,stats,bng,bnb,N);

    gemm(stream,hN,128,N,128,128,postp,postb,P1,1);

    pool_k<<<(N+3)/4,256,0,stream>>>(P1,batch,iflag,pooled,cnt,N,NG);
    final_k<<<NG,64,0,stream>>>(pooled,cnt,outW,outb,(float*)d_out);
}

// Round 14
// 2980.351 us; speedup vs baseline: 1.3085x; 1.0644x over previous
//
#include <hip/hip_runtime.h>

#define NCONV_DEF 4
#define SCH 1024

typedef unsigned short u16;
typedef __attribute__((ext_vector_type(8))) short s8v;      // MFMA bf16 A/B frag
typedef __attribute__((ext_vector_type(4))) float f4v;      // MFMA C/D frag
typedef __attribute__((ext_vector_type(8))) unsigned short u16x8;

__device__ __forceinline__ float sigm_f(float x){ return 1.f/(1.f+__expf(-x)); }
__device__ __forceinline__ float silu_f(float x){ return x/(1.f+__expf(-x)); }
__device__ __forceinline__ float b2f(u16 h){ union{unsigned u; float f;} v; v.u=(unsigned)h<<16; return v.f; }
__device__ __forceinline__ u16 f2b(float f){ union{float f; unsigned u;} v; v.f=f; unsigned r=v.u+0x7fffu+((v.u>>16)&1u); return (u16)(r>>16); }
__device__ __forceinline__ float ldAv(const float* p, size_t i){ return p[i]; }
__device__ __forceinline__ float ldAv(const u16* p, size_t i){ return b2f(p[i]); }

#define EPS_ 136   // epilogue LDS row stride in u16 (272B)

__global__ __launch_bounds__(256) void zero_f_k(float* p, long n){
    long i=(long)blockIdx.x*256+threadIdx.x, st=(long)gridDim.x*256;
    for(;i<n;i+=st) p[i]=0.f;
}
__global__ __launch_bounds__(256) void zero_i_k(int* p, long n){
    long i=(long)blockIdx.x*256+threadIdx.x, st=(long)gridDim.x*256;
    for(;i<n;i+=st) p[i]=0;
}
__global__ void diag_k(float* out, int n, float v){
    int i=blockIdx.x*256+threadIdx.x; if(i<n) out[i]=v;
}
__global__ void probe_k(const int* ei, const int* eil, const int* batch, int nb, int* flag){
    if(threadIdx.x||blockIdx.x) return;
    int a=2,b=2,c=2;
    for(int k=0;k<64;k++){ if(ei[2*k+1]!=0) a=1; if(eil[2*k+1]!=0) b=1; }
    int base=nb-128;
    for(int k=0;k<64;k++){ if(batch[base+2*k+1]!=0) c=1; }
    flag[0]=a; flag[1]=b; flag[2]=c;
}

// ---------------- CSR build ----------------------------------------------------
__global__ __launch_bounds__(256)
void hist_k(const int* __restrict__ idx, const int* __restrict__ iflag, int fi,
            int* __restrict__ cnt, int Ne, int Nn){
    int e=blockIdx.x*256+threadIdx.x; if(e>=Ne) return;
    int st=iflag[fi];
    int i=idx[(size_t)e*st]; i=i<0?0:(i>=Nn?Nn-1:i);
    atomicAdd(&cnt[i],1);
}
__global__ __launch_bounds__(256)
void scan1_k(const int* cnt, int* tot, int n){
    __shared__ int sh[256];
    int base=blockIdx.x*SCH, s=0;
    for(int t=threadIdx.x;t<SCH;t+=256){ int i=base+t; s+=(i<n)?cnt[i]:0; }
    sh[threadIdx.x]=s; __syncthreads();
    for(int o=128;o;o>>=1){ if(threadIdx.x<o) sh[threadIdx.x]+=sh[threadIdx.x+o]; __syncthreads(); }
    if(threadIdx.x==0) tot[blockIdx.x]=sh[0];
}
__global__ void scan2_k(int* tot, int nb){
    if(threadIdx.x==0&&blockIdx.x==0){ int acc=0; for(int i=0;i<nb;i++){int v=tot[i]; tot[i]=acc; acc+=v;} }
}
__global__ __launch_bounds__(256)
void scan3_k(const int* cnt, const int* tot, int* off, int n, int total){
    __shared__ int sh[256];
    int b=blockIdx.x, t4=b*SCH+threadIdx.x*4;
    int v0=(t4+0<n)?cnt[t4+0]:0, v1=(t4+1<n)?cnt[t4+1]:0;
    int v2=(t4+2<n)?cnt[t4+2]:0, v3=(t4+3<n)?cnt[t4+3]:0;
    int ls=v0+v1+v2+v3;
    sh[threadIdx.x]=ls; __syncthreads();
    for(int o=1;o<256;o<<=1){
        int val=(threadIdx.x>=o)?sh[threadIdx.x-o]:0; __syncthreads();
        sh[threadIdx.x]+=val; __syncthreads();
    }
    int excl=sh[threadIdx.x]-ls+tot[b];
    if(t4+0<n) off[t4+0]=excl;
    if(t4+1<n) off[t4+1]=excl+v0;
    if(t4+2<n) off[t4+2]=excl+v0+v1;
    if(t4+3<n) off[t4+3]=excl+v0+v1+v2;
    if(b==(int)gridDim.x-1&&threadIdx.x==255) off[n]=total;
}
__global__ __launch_bounds__(256)
void fill_k(const int* __restrict__ idx, const int* __restrict__ iflag, int fi, long joff,
            const int* __restrict__ off, int* __restrict__ cur,
            int* __restrict__ list, int* __restrict__ jlist, int Ne, int Nn){
    int e=blockIdx.x*256+threadIdx.x; if(e>=Ne) return;
    int st=iflag[fi];
    int i=idx[(size_t)e*st]; i=i<0?0:(i>=Nn?Nn-1:i);
    int j=idx[((size_t)joff+e)*st]; j=j<0?0:(j>=Nn?Nn-1:j);
    int pos=off[i]+atomicAdd(&cur[i],1);
    list[pos]=e; jlist[pos]=j;
}

// ---------------- weight pack: W[K][128] f32 -> Wp[128][Kp] bf16 ---------------
__global__ __launch_bounds__(256)
void pack_w_k(const float* __restrict__ W, u16* __restrict__ Wp, int K, int Kp){
    int i=blockIdx.x*256+threadIdx.x;
    if(i>=128*Kp) return;
    int n=i/Kp, k=i-n*Kp;
    Wp[i] = (k<K) ? f2b(W[(size_t)k*128+n]) : (u16)0;
}

// ---------------- MFMA GEMM: C[M,128] = A[M,K] @ W[K,128] (+bias)(+silu) -------
template<typename TA, int ACT>
__global__ __launch_bounds__(256)
void gemm_k(const TA* __restrict__ A, int lda, int M, int K, int Kp,
            const u16* __restrict__ Wp, const float* __restrict__ bias,
            u16* __restrict__ C)
{
    __shared__ __align__(16) u16 As[64*72];
    __shared__ __align__(16) u16 Bs[128*72];
    const int tid=threadIdx.x, row0=blockIdx.x*64;
    const int w=tid>>6, l=tid&63, lr=l&15, kg=l>>4;
    f4v zz={0.f,0.f,0.f,0.f};
    f4v acc[8];
#pragma unroll
    for(int i=0;i<8;++i) acc[i]=zz;

    for(int kt=0;kt<Kp;kt+=64){
        {
            int r=tid>>2, c0=(tid&3)*16;
            int gr=row0+r;
            bool vec=false;
            if constexpr (sizeof(TA)==2) vec=((K&63)==0);
            if(vec){
                const u16* src=(const u16*)(const void*)A+(size_t)gr*lda+kt+c0;
                u16x8 v0={0,0,0,0,0,0,0,0}, v1={0,0,0,0,0,0,0,0};
                if(gr<M){ v0=*(const u16x8*)src; v1=*(const u16x8*)(src+8); }
                *(u16x8*)&As[r*72+c0]=v0;
                *(u16x8*)&As[r*72+c0+8]=v1;
            } else {
                for(int c=c0;c<c0+16;++c){
                    int k=kt+c;
                    float v=(gr<M&&k<K)?ldAv(A,(size_t)gr*lda+k):0.f;
                    As[r*72+c]=f2b(v);
                }
            }
        }
        {
            int n=tid>>1, k0=(tid&1)*32;
            const u16* src=Wp+(size_t)n*Kp+kt+k0;
            *(u16x8*)&Bs[n*72+k0]   =*(const u16x8*)(src);
            *(u16x8*)&Bs[n*72+k0+8] =*(const u16x8*)(src+8);
            *(u16x8*)&Bs[n*72+k0+16]=*(const u16x8*)(src+16);
            *(u16x8*)&Bs[n*72+k0+24]=*(const u16x8*)(src+24);
        }
        __syncthreads();
        const int arow=w*16+lr;
#pragma unroll
        for(int kk=0;kk<64;kk+=32){
            s8v a=*(const s8v*)&As[arow*72+kk+kg*8];
#pragma unroll
            for(int ct=0;ct<8;++ct){
                s8v bfr=*(const s8v*)&Bs[(ct*16+lr)*72+kk+kg*8];
                acc[ct]=__builtin_amdgcn_mfma_f32_16x16x32_bf16(a,bfr,acc[ct],0,0,0);
            }
        }
        __syncthreads();
    }
    u16* ep=Bs;
#pragma unroll
    for(int ct=0;ct<8;++ct){
        int col=ct*16+lr;
        float bv=bias?bias[col]:0.f;
#pragma unroll
        for(int reg=0;reg<4;++reg){
            float v=acc[ct][reg]+bv;
            if(ACT) v=silu_f(v);
            ep[(w*16+kg*4+reg)*EPS_+col]=f2b(v);
        }
    }
    __syncthreads();
    {
        int ar=tid>>2, gr=row0+ar;
        if(gr<M){
            u16* crow=C+(size_t)gr*128+(tid&3)*32;
            const u16* hrow=&ep[ar*EPS_+(tid&3)*32];
#pragma unroll
            for(int c4=0;c4<4;++c4)
                *(u16x8*)(crow+c4*8)=*(const u16x8*)(hrow+c4*8);
        }
    }
}

// ---------------- fused node update GEMM (IN PLACE on X) -----------------------
// X = X + silu(LN(X@Wsrc + bias + U))
__global__ __launch_bounds__(256)
void gemmz_k(u16* __restrict__ X, int M,
             const u16* __restrict__ Wp, const float* __restrict__ bias,
             const u16* __restrict__ U,
             const float* __restrict__ g, const float* __restrict__ b)
{
    __shared__ __align__(16) u16 As[2][64*68];
    __shared__ __align__(16) u16 Bs[128*136];
    const int tid=threadIdx.x, row0=blockIdx.x*64;
    const int w=tid>>6, l=tid&63, lr=l&15, kg=l>>4;
    u16* ep=&As[0][0];
    const int ar=tid>>2, gr=row0+ar;
    {
        u16x8 z8={0,0,0,0,0,0,0,0};
        u16x8 u0=z8,u1=z8,u2=z8,u3=z8;
        if(gr<M){
            const u16* ur=U+(size_t)gr*128+(tid&3)*32;
            u0=*(const u16x8*)(ur); u1=*(const u16x8*)(ur+8);
            u2=*(const u16x8*)(ur+16); u3=*(const u16x8*)(ur+24);
        }
        u16* d=&ep[ar*EPS_+(tid&3)*32];
        *(u16x8*)(d)=u0; *(u16x8*)(d+8)=u1; *(u16x8*)(d+16)=u2; *(u16x8*)(d+24)=u3;
    }
    __syncthreads();
    f4v acc[8];
#pragma unroll
    for(int ct=0;ct<8;++ct){
        int col=ct*16+lr;
        float bv=bias[col];
#pragma unroll
        for(int reg=0;reg<4;++reg)
            acc[ct][reg]=b2f(ep[(w*16+kg*4+reg)*EPS_+col])+bv;
    }
    __syncthreads();

    {
        int c0=(tid&3)*16;
        const u16* src=X+(size_t)gr*128;
        u16x8 z8={0,0,0,0,0,0,0,0};
        u16x8 v0=z8,v1=z8,v2=z8,v3=z8;
        if(gr<M){
            v0=*(const u16x8*)(src+c0);    v1=*(const u16x8*)(src+c0+8);
            v2=*(const u16x8*)(src+64+c0); v3=*(const u16x8*)(src+64+c0+8);
        }
        *(u16x8*)&As[0][ar*68+c0]=v0;  *(u16x8*)&As[0][ar*68+c0+8]=v1;
        *(u16x8*)&As[1][ar*68+c0]=v2;  *(u16x8*)&As[1][ar*68+c0+8]=v3;
        int bn=tid>>1, bk=(tid&1)*64;
        const u16* wsrc=Wp+(size_t)bn*128+bk;
#pragma unroll
        for(int q=0;q<8;++q)
            *(u16x8*)&Bs[bn*136+bk+q*8]=*(const u16x8*)(wsrc+q*8);
    }
    __syncthreads();
    const int arow=w*16+lr;
#pragma unroll
    for(int kt=0;kt<2;++kt){
#pragma unroll
        for(int kk=0;kk<64;kk+=32){
            s8v a=*(const s8v*)&As[kt][arow*68+kk+kg*8];
#pragma unroll
            for(int ct=0;ct<8;++ct){
                s8v bfr=*(const s8v*)&Bs[(ct*16+lr)*136+kt*64+kk+kg*8];
                acc[ct]=__builtin_amdgcn_mfma_f32_16x16x32_bf16(a,bfr,acc[ct],0,0,0);
            }
        }
    }
    float sum[4]={0.f,0.f,0.f,0.f}, sq[4]={0.f,0.f,0.f,0.f};
#pragma unroll
    for(int ct=0;ct<8;++ct)
#pragma unroll
        for(int reg=0;reg<4;++reg){
            float v=acc[ct][reg];
            sum[reg]+=v; sq[reg]+=v*v;
        }
#pragma unroll
    for(int m=1;m<16;m<<=1)
#pragma unroll
        for(int reg=0;reg<4;++reg){
            sum[reg]+=__shfl_xor(sum[reg],m,64);
            sq[reg] +=__shfl_xor(sq[reg], m,64);
        }
    float mean[4], rstd[4];
#pragma unroll
    for(int reg=0;reg<4;++reg){
        mean[reg]=sum[reg]*(1.f/128.f);
        float var=sq[reg]*(1.f/128.f)-mean[reg]*mean[reg];
        rstd[reg]=rsqrtf(var+1e-5f);
    }
    __syncthreads();
#pragma unroll
    for(int ct=0;ct<8;++ct){
        int col=ct*16+lr;
        float gv=g[col], bv=b[col];
#pragma unroll
        for(int reg=0;reg<4;++reg){
            float h=gv*(acc[ct][reg]-mean[reg])*rstd[reg]+bv;
            ep[(w*16+kg*4+reg)*EPS_+col]=f2b(silu_f(h));
        }
    }
    if(gr<M){
        u16* xrow=X+(size_t)gr*128+(tid&3)*32;
        const u16* hrow=&ep[ar*EPS_+(tid&3)*32];
#pragma unroll
        for(int c4=0;c4<4;++c4){
            u16x8 xv=*(const u16x8*)(xrow+c4*8);
            u16x8 hv=*(const u16x8*)(hrow+c4*8);
            u16x8 ov;
#pragma unroll
            for(int j=0;j<8;++j) ov[j]=f2b(b2f(xv[j])+b2f(hv[j]));
            *(u16x8*)(xrow+c4*8)=ov;
        }
    }
}

// ---------------- fused CSR gather v3: 4 nodes/wave, uint4, prefetch -----------
template<int FIN, int HASPREV>
__global__ __launch_bounds__(256)
void gather_k(const u16* __restrict__ e, const u16* __restrict__ P1,
              u16* __restrict__ U,
              const int* __restrict__ off, const int* __restrict__ list,
              const int* __restrict__ jlist,
              int Nn, int c0, int c1)
{
    int wid=threadIdx.x>>6, lane=threadIdx.x&63;
    int q=lane>>4, sl=lane&15;
    int n=blockIdx.x*16+wid*4+q;
    int beg=0,end=0;
    if(n<Nn){ beg=off[n]; end=off[n+1]; }
    const int d8=sl*8;
    uint4 uprev=make_uint4(0,0,0,0);
    if(FIN&&HASPREV&&n<Nn) uprev=*(const uint4*)(U+(size_t)n*128+d8);

    float es[8]={0.f,0.f,0.f,0.f,0.f,0.f,0.f,0.f};
    float a[8]={0.f,0.f,0.f,0.f,0.f,0.f,0.f,0.f};
    int k=beg;
    uint4 ev_n=make_uint4(0,0,0,0), pv_n=make_uint4(0,0,0,0);
    bool in_n=false;
    if(k<end){
        int eid=list[k], j=jlist[k];
        in_n=(j>=c0)&&(j<c1);
        if(FIN||in_n) ev_n=*(const uint4*)(e+(size_t)eid*128+d8);
        if(in_n)      pv_n=*(const uint4*)(P1+(size_t)(j-c0)*128+d8);
    }
    while(k<end){
        uint4 ev=ev_n, pv=pv_n; bool in=in_n;
        int kn=k+1;
        if(kn<end){
            int eid=list[kn], j=jlist[kn];
            in_n=(j>=c0)&&(j<c1);
            ev_n=make_uint4(0,0,0,0); pv_n=make_uint4(0,0,0,0);
            if(FIN||in_n) ev_n=*(const uint4*)(e+(size_t)eid*128+d8);
            if(in_n)      pv_n=*(const uint4*)(P1+(size_t)(j-c0)*128+d8);
        }
        unsigned ew[4]={ev.x,ev.y,ev.z,ev.w};
        unsigned pw[4]={pv.x,pv.y,pv.z,pv.w};
        float s[8];
#pragma unroll
        for(int t=0;t<4;++t){
            s[2*t]  =sigm_f(b2f((u16)(ew[t]&0xffff)));
            s[2*t+1]=sigm_f(b2f((u16)(ew[t]>>16)));
        }
        if(FIN){
#pragma unroll
            for(int t=0;t<8;++t) es[t]+=s[t];
        }
        if(in){
#pragma unroll
            for(int t=0;t<4;++t){
                a[2*t]  +=s[2*t]  *b2f((u16)(pw[t]&0xffff));
                a[2*t+1]+=s[2*t+1]*b2f((u16)(pw[t]>>16));
            }
        }
        k=kn;
    }
    if(n>=Nn) return;
    uint4* up=(uint4*)(U+(size_t)n*128+d8);
    uint4 o;
    if(!FIN){
        o.x=((unsigned)f2b(a[0]))|((unsigned)f2b(a[1])<<16);
        o.y=((unsigned)f2b(a[2]))|((unsigned)f2b(a[3])<<16);
        o.z=((unsigned)f2b(a[4]))|((unsigned)f2b(a[5])<<16);
        o.w=((unsigned)f2b(a[6]))|((unsigned)f2b(a[7])<<16);
    } else {
        if(HASPREV){
            unsigned uw[4]={uprev.x,uprev.y,uprev.z,uprev.w};
#pragma unroll
            for(int t=0;t<4;++t){
                a[2*t]  +=b2f((u16)(uw[t]&0xffff));
                a[2*t+1]+=b2f((u16)(uw[t]>>16));
            }
        }
        float r[8];
#pragma unroll
        for(int t=0;t<8;++t) r[t]=1.f/(es[t]+1e-5f);
        o.x=((unsigned)f2b(a[0]*r[0]))|((unsigned)f2b(a[1]*r[1])<<16);
        o.y=((unsigned)f2b(a[2]*r[2]))|((unsigned)f2b(a[3]*r[3])<<16);
        o.z=((unsigned)f2b(a[4]*r[4]))|((unsigned)f2b(a[5]*r[5])<<16);
        o.w=((unsigned)f2b(a[6]*r[6]))|((unsigned)f2b(a[7]*r[7])<<16);
    }
    *up=o;
}

// ---------------- fused edge update (r11 version): 128 edges, 512 thr, dbuf ----
__global__ __launch_bounds__(512)
void edgez_k(u16* __restrict__ e, const u16* __restrict__ x,
             const int* __restrict__ idx, long joff,
             const int* __restrict__ iflag, int fi,
             const u16* __restrict__ Wep, const float* __restrict__ be,
             const float* __restrict__ g, const float* __restrict__ b,
             int Ne, int Nn)
{
    __shared__ __align__(16) u16 As[2][128*68];
    __shared__ __align__(16) u16 Bs[2][128*68];
    __shared__ int rid[256];
    const int tid=threadIdx.x, row0=blockIdx.x*128;
    const int w=tid>>6, l=tid&63, lr=l&15, kg=l>>4;
    int st=iflag[fi];
    if(tid<256){
        int r=tid&127, eid=row0+r; if(eid>=Ne) eid=Ne-1;
        long elem=(tid<128)?(long)eid:(joff+eid);
        int v=idx[(size_t)elem*st]; v=v<0?0:(v>=Nn?Nn-1:v);
        rid[tid]=v;
    }
    __syncthreads();
    const int ar=tid>>2, ac=(tid&3)*16;
    const int bn=tid>>2, bk=(tid&3)*16;
    int eidA=row0+ar; if(eidA>=Ne) eidA=Ne-1;
    const u16* aptr0=x+(size_t)rid[ar]*128;
    const u16* aptr1=x+(size_t)rid[128+ar]*128;
    const u16* aptr2=e+(size_t)eidA*128;

    f4v zz={0.f,0.f,0.f,0.f};
    f4v acc[8];
#pragma unroll
    for(int i=0;i<8;++i) acc[i]=zz;

    u16x8 a0,a1,b0,b1;
    u16x8 er0,er1,er2,er3;
    {
        const u16* src=aptr0+ac;
        a0=*(const u16x8*)src; a1=*(const u16x8*)(src+8);
        const u16* wsrc=Wep+(size_t)bn*384+bk;
        b0=*(const u16x8*)wsrc; b1=*(const u16x8*)(wsrc+8);
    }
#pragma unroll
    for(int s=0;s<6;++s){
        const int buf=s&1;
        *(u16x8*)&As[buf][ar*68+ac]  =a0;
        *(u16x8*)&As[buf][ar*68+ac+8]=a1;
        *(u16x8*)&Bs[buf][bn*68+bk]  =b0;
        *(u16x8*)&Bs[buf][bn*68+bk+8]=b1;
        if(s<5){
            const int sn=s+1, sec=sn>>1, half=sn&1;
            const u16* src=(sec==0?aptr0:(sec==1?aptr1:aptr2))+half*64+ac;
            a0=*(const u16x8*)src; a1=*(const u16x8*)(src+8);
            if(sec==2){ if(half==0){ er0=a0; er1=a1; } else { er2=a0; er3=a1; } }
            const u16* wsrc=Wep+(size_t)bn*384+sn*64+bk;
            b0=*(const u16x8*)wsrc; b1=*(const u16x8*)(wsrc+8);
        }
        __syncthreads();
        __builtin_amdgcn_s_setprio(1);
        const int arow=w*16+lr;
#pragma unroll
        for(int kk=0;kk<64;kk+=32){
            s8v a=*(const s8v*)&As[buf][arow*68+kk+kg*8];
#pragma unroll
            for(int ct=0;ct<8;++ct){
                s8v bfr=*(const s8v*)&Bs[buf][(ct*16+lr)*68+kk+kg*8];
                acc[ct]=__builtin_amdgcn_mfma_f32_16x16x32_bf16(a,bfr,acc[ct],0,0,0);
            }
        }
        __builtin_amdgcn_s_setprio(0);
    }
    float sum[4]={0.f,0.f,0.f,0.f}, sq[4]={0.f,0.f,0.f,0.f};
#pragma unroll
    for(int ct=0;ct<8;++ct){
        float bev=be[ct*16+lr];
#pragma unroll
        for(int reg=0;reg<4;++reg){
            float v=acc[ct][reg]+bev;
            acc[ct][reg]=v;
            sum[reg]+=v; sq[reg]+=v*v;
        }
    }
#pragma unroll
    for(int m=1;m<16;m<<=1){
#pragma unroll
        for(int reg=0;reg<4;++reg){
            sum[reg]+=__shfl_xor(sum[reg],m,64);
            sq[reg] +=__shfl_xor(sq[reg], m,64);
        }
    }
    float mean[4], rstd[4];
#pragma unroll
    for(int reg=0;reg<4;++reg){
        mean[reg]=sum[reg]*(1.f/128.f);
        float var=sq[reg]*(1.f/128.f)-mean[reg]*mean[reg];
        rstd[reg]=rsqrtf(var+1e-5f);
    }
    __syncthreads();
    u16* ep=&Bs[0][0];
#pragma unroll
    for(int ct=0;ct<8;++ct){
        int col=ct*16+lr;
        float gv=g[col], bv=b[col];
#pragma unroll
        for(int reg=0;reg<4;++reg){
            float hh=gv*(acc[ct][reg]-mean[reg])*rstd[reg]+bv;
            ep[(w*16+kg*4+reg)*EPS_+col]=f2b(silu_f(hh));
        }
    }
    {
        int eid=row0+ar;
        if(eid<Ne){
            u16* erow=e+(size_t)eid*128;
            const u16* hr=&ep[ar*EPS_];
            u16x8 h0=*(const u16x8*)(hr+ac),    h1=*(const u16x8*)(hr+ac+8);
            u16x8 h2=*(const u16x8*)(hr+64+ac), h3=*(const u16x8*)(hr+64+ac+8);
            u16x8 o0,o1,o2,o3;
#pragma unroll
            for(int j=0;j<8;++j){
                o0[j]=f2b(b2f(er0[j])+b2f(h0[j]));
                o1[j]=f2b(b2f(er1[j])+b2f(h1[j]));
                o2[j]=f2b(b2f(er2[j])+b2f(h2[j]));
                o3[j]=f2b(b2f(er3[j])+b2f(h3[j]));
            }
            *(u16x8*)(erow+ac)=o0;    *(u16x8*)(erow+ac+8)=o1;
            *(u16x8*)(erow+64+ac)=o2; *(u16x8*)(erow+64+ac+8)=o3;
        }
    }
}

// ---------------- BatchNorm / pool / head --------------------------------------
__global__ __launch_bounds__(256)
void bn_stats_k(const u16* __restrict__ h, float* __restrict__ st, int N){
    int t=blockIdx.x*256+threadIdx.x;
    int d=t&127, r0=t>>7, rstride=(gridDim.x*256)>>7;
    float s=0.f,q=0.f;
    for(int r=r0;r<N;r+=rstride){ float v=b2f(h[(size_t)r*128+d]); s+=v; q+=v*v; }
    atomicAdd(&st[d],s); atomicAdd(&st[128+d],q);
}
__global__ __launch_bounds__(256)
void bn_apply_k(u16* __restrict__ h, const float* __restrict__ st,
                const float* __restrict__ g, const float* __restrict__ b, int N){
    int t=blockIdx.x*256+threadIdx.x;
    if(t>=N*128) return;
    int d=t&127;
    float inv=1.f/(float)N;
    float m=st[d]*inv, var=st[128+d]*inv-m*m;
    float v=g[d]*(b2f(h[t])-m)*rsqrtf(var+1e-5f)+b[d];
    h[t]=f2b(silu_f(v));
}
__global__ __launch_bounds__(256)
void pool_k(const u16* __restrict__ o, const int* __restrict__ batch,
            const int* __restrict__ iflag,
            float* __restrict__ pooled, float* __restrict__ cnt, int N, int NG){
    int st=iflag[2];
    int wid=threadIdx.x>>6, lane=threadIdx.x&63;
    int n=blockIdx.x*4+wid; if(n>=N) return;
    int gi=batch[(size_t)n*st]; gi=gi<0?0:(gi>=NG?NG-1:gi);
    atomicAdd(&pooled[(size_t)gi*128+lane],    b2f(o[(size_t)n*128+lane]));
    atomicAdd(&pooled[(size_t)gi*128+64+lane], b2f(o[(size_t)n*128+64+lane]));
    if(lane==0) atomicAdd(&cnt[gi],1.f);
}
__global__ void final_k(const float* __restrict__ pooled, const float* __restrict__ cnt,
                        const float* __restrict__ oW, const float* __restrict__ ob,
                        float* __restrict__ out){
    int gi=blockIdx.x, lane=threadIdx.x;
    float v=pooled[(size_t)gi*128+lane]*oW[lane]
           +pooled[(size_t)gi*128+64+lane]*oW[64+lane];
    for(int m=32;m;m>>=1) v+=__shfl_xor(v,m,64);
    if(lane==0) out[gi]=v/fmaxf(cnt[gi],1.f)+ob[0];
}

// -------------------------------------------------------------------------------
template<typename TA>
static inline void gemm(hipStream_t s, const TA* A, int lda, int M, int K, int Kp,
                        const u16* Wp, const float* bias, u16* C, int act){
    dim3 grid((M+63)/64);
    if(act) gemm_k<TA,1><<<grid,256,0,s>>>(A,lda,M,K,Kp,Wp,bias,C);
    else    gemm_k<TA,0><<<grid,256,0,s>>>(A,lda,M,K,Kp,Wp,bias,C);
}

static inline void build_csr(hipStream_t s, const int* idx, int fi, long joff, const int* iflag,
                             int Ne, int Nn, int* off, int* cur, int* list, int* jlist, int* tot){
    int nb=(Nn+SCH-1)/SCH;
    zero_i_k<<<256,256,0,s>>>(cur,Nn);
    hist_k<<<(Ne+255)/256,256,0,s>>>(idx,iflag,fi,cur,Ne,Nn);
    scan1_k<<<nb,256,0,s>>>(cur,tot,Nn);
    scan2_k<<<1,1,0,s>>>(tot,nb);
    scan3_k<<<nb,256,0,s>>>(cur,tot,off,Nn,Ne);
    zero_i_k<<<256,256,0,s>>>(cur,Nn);
    fill_k<<<(Ne+255)/256,256,0,s>>>(idx,iflag,fi,joff,off,cur,list,jlist,Ne,Nn);
}

static inline void pack_w(hipStream_t s, const float* W, u16* Wp, int K, int Kp){
    pack_w_k<<<(128*Kp+255)/256,256,0,s>>>(W,Wp,K,Kp);
}

extern "C" void kernel_launch(void* const* d_in, const int* in_sizes, int n_in,
                              void* d_out, int out_size, void* d_ws, size_t ws_size,
                              hipStream_t stream)
{
    const float* x_in =(const float*)d_in[0];
    const float* ea   =(const float*)d_in[1];
    const float* eal  =(const float*)d_in[2];
    const int*   ei   =(const int*)d_in[3];
    const int*   eil  =(const int*)d_in[4];
    const int*   batch=(const int*)d_in[5];
    const float* pre1W=(const float*)d_in[6];  const float* pre1b=(const float*)d_in[7];
    const float* pre2W=(const float*)d_in[8];  const float* pre2b=(const float*)d_in[9];
    const float* pre3W=(const float*)d_in[10]; const float* pre3b=(const float*)d_in[11];
    const float* lWsrc=(const float*)d_in[12]; const float* lbsrc=(const float*)d_in[13];
    const float* lWdst=(const float*)d_in[14]; const float* lbdst=(const float*)d_in[15];
    const float* lWe  =(const float*)d_in[16]; const float* lbe  =(const float*)d_in[17];
    const float* lnxg =(const float*)d_in[18]; const float* lnxb =(const float*)d_in[19];
    const float* lneg =(const float*)d_in[20]; const float* lneb =(const float*)d_in[21];
    const float* aWsrc=(const float*)d_in[22]; const float* absrc=(const float*)d_in[23];
    const float* aWdst=(const float*)d_in[24]; const float* abdst=(const float*)d_in[25];
    const float* aWe  =(const float*)d_in[26]; const float* abe  =(const float*)d_in[27];
    const float* anxg =(const float*)d_in[28]; const float* anxb =(const float*)d_in[29];
    const float* aneg =(const float*)d_in[30]; const float* aneb =(const float*)d_in[31];
    const float* bng  =(const float*)d_in[32]; const float* bnb  =(const float*)d_in[33];
    const float* postW=(const float*)d_in[34]; const float* postb=(const float*)d_in[35];
    const float* outW =(const float*)d_in[36]; const float* outb =(const float*)d_in[37];
    (void)n_in;

    const int N =in_sizes[5];
    const int E =in_sizes[3]/2;
    const int EL=in_sizes[4]/2;
    const int NG=out_size;
    const int CH=(E+1)/2;

    char* base=(char*)d_ws;
    size_t off=0;
    auto alloc=[&](size_t bytes)->char*{
        char* p=base+off; off=(off+bytes+255)&~(size_t)255; return p;
    };
    u16* hN   =(u16*)alloc((size_t)N*128*2);
    u16* hE   =(u16*)alloc((size_t)E*128*2);
    u16* hL   =(u16*)alloc((size_t)EL*128*2);
    u16* U    =(u16*)alloc((size_t)E*128*2);
    u16* P1   =(u16*)alloc((size_t)CH*128*2);
    int* off_l=(int*)alloc((size_t)(E+1)*4);
    int* cur_l=(int*)alloc((size_t)E*4);
    int* list_l=(int*)alloc((size_t)EL*4);
    int* jlist_l=(int*)alloc((size_t)EL*4);
    int* off_a=(int*)alloc((size_t)(N+1)*4);
    int* cur_a=(int*)alloc((size_t)N*4);
    int* list_a=(int*)alloc((size_t)E*4);
    int* jlist_a=(int*)alloc((size_t)E*4);
    int* tot  =(int*)alloc(4096);
    int* iflag=(int*)alloc(64);
    float* stats =(float*)alloc(256*4);
    float* pooled=(float*)alloc((size_t)NG*128*4);
    float* cnt   =(float*)alloc((size_t)NG*4);
    u16* pre1p=(u16*)alloc(128*128*2);
    u16* pre2p=(u16*)alloc(128*64*2);
    u16* pre3p=(u16*)alloc(128*64*2);
    u16* postp=(u16*)alloc(128*128*2);
    u16 *lsrcp[4],*ldstp[4],*lWep[4],*asrcp[4],*adstp[4],*aWep[4];
    for(int i=0;i<4;i++){
        lsrcp[i]=(u16*)alloc(128*128*2);
        ldstp[i]=(u16*)alloc(128*128*2);
        lWep[i] =(u16*)alloc(128*384*2);
        asrcp[i]=(u16*)alloc(128*128*2);
        adstp[i]=(u16*)alloc(128*128*2);
        aWep[i] =(u16*)alloc(128*384*2);
    }
    if(off>ws_size){
        diag_k<<<(NG+255)/256,256,0,stream>>>((float*)d_out,NG,(float)(ws_size>>20)+0.25f);
        return;
    }

    probe_k<<<1,64,0,stream>>>(ei,eil,batch,N,iflag);
    build_csr(stream,eil,1,EL,iflag,EL,E,off_l,cur_l,list_l,jlist_l,tot);
    build_csr(stream,ei, 0,E, iflag,E, N,off_a,cur_a,list_a,jlist_a,tot);

    pack_w(stream,pre1W,pre1p,92,128);
    pack_w(stream,pre2W,pre2p,50,64);
    pack_w(stream,pre3W,pre3p,40,64);
    pack_w(stream,postW,postp,128,128);
    for(int i=0;i<4;i++){
        pack_w(stream,lWsrc+(size_t)i*128*128,lsrcp[i],128,128);
        pack_w(stream,lWdst+(size_t)i*128*128,ldstp[i],128,128);
        pack_w(stream,lWe  +(size_t)i*384*128,lWep[i],384,384);
        pack_w(stream,aWsrc+(size_t)i*128*128,asrcp[i],128,128);
        pack_w(stream,aWdst+(size_t)i*128*128,adstp[i],128,128);
        pack_w(stream,aWe  +(size_t)i*384*128,aWep[i],384,384);
    }

    gemm(stream,x_in,92,N, 92,128,pre1p,pre1b,hN,1);
    gemm(stream,ea,  50,E, 50, 64,pre2p,pre2b,hE,1);
    gemm(stream,eal, 40,EL,40, 64,pre3p,pre3b,hL,1);

    for(int l=0;l<NCONV_DEF;++l){
        {   // ===== line conv: nodes=hE (E), edges=hL (EL) =====
            gemm(stream,hE,128,CH,128,128,ldstp[l],lbdst+l*128,P1,0);
            gather_k<0,0><<<(E+15)/16,256,0,stream>>>(hL,P1,U,off_l,list_l,jlist_l,E,0,CH);
            gemm(stream,hE+(size_t)CH*128,128,E-CH,128,128,ldstp[l],lbdst+l*128,P1,0);
            gather_k<1,1><<<(E+15)/16,256,0,stream>>>(hL,P1,U,off_l,list_l,jlist_l,E,CH,E);
            edgez_k<<<(EL+127)/128,512,0,stream>>>(hL,hE,eil,EL,iflag,1,
                                                   lWep[l],lbe+l*128,lneg+l*128,lneb+l*128,EL,E);
            gemmz_k<<<(E+63)/64,256,0,stream>>>(hE,E,lsrcp[l],lbsrc+l*128,U,
                                                lnxg+l*128,lnxb+l*128);
        }
        {   // ===== atom conv: nodes=hN (N), edges=hE (E) =====
            gemm(stream,hN,128,N,128,128,adstp[l],abdst+l*128,P1,0);
            gather_k<1,0><<<(N+15)/16,256,0,stream>>>(hE,P1,U,off_a,list_a,jlist_a,N,0,N);
            edgez_k<<<(E+127)/128,512,0,stream>>>(hE,hN,ei,E,iflag,0,
                                                  aWep[l],abe+l*128,aneg+l*128,aneb+l*128,E,N);
            gemmz_k<<<(N+63)/64,256,0,stream>>>(hN,N,asrcp[l],absrc+l*128,U,
                                                anxg+l*128,anxb+l*128);
        }
    }

    zero_f_k<<<64,256,0,stream>>>(stats,256);
    zero_f_k<<<64,256,0,stream>>>(pooled,(long)NG*128);
    zero_f_k<<<1,256,0,stream>>>(cnt,NG);
    bn_stats_k<<<256,256,0,stream>>>(hN,stats,N);
    bn_apply_k<<<(N*128+255)/256,256,0,stream>>>(hN,stats,bng,bnb,N);

    gemm(stream,hN,128,N,128,128,postp,postb,P1,1);

    pool_k<<<(N+3)/4,256,0,stream>>>(P1,batch,iflag,pooled,cnt,N,NG);
    final_k<<<NG,64,0,stream>>>(pooled,cnt,outW,outb,(float*)d_out);
}